// Round 11
// baseline (113.835 us; speedup 1.0000x reference)
//
#include <hip/hip_runtime.h>
#include <stdint.h>

// PETNNCell collapse (proven analytically):
//   T_t == 0, m == 1;  C_new = I_t + Z_c;  h = sigmoid(X @ W_h[:, :512]^T + b_h)
//   S_new = sigmoid((1 - Z_w)*S_prev + Z_w*h + X)
//
// R11: faithful m201 phase ordering. R5-R10 all (a) saturated the register
// budget exactly (no compiler read-ahead possible) and (b) placed ds_reads
// AFTER the phase barrier (serial read->wait->MFMA). Fix: wave tile 64x32
// per output (acc 64, ~80 spare VGPRs), 3-buffer LDS pipeline (prefetch
// distance 2), per phase: reads BEFORE barrier -> glds issue -> counted
// vmcnt (6/4, never 0 until the last 2 tiles) -> barrier -> lgkm0+SB0 ->
// setprio-wrapped 16-MFMA cluster -> barrier.

#define BROWS 16384
#define DDIM  512

typedef __bf16 bf16x8 __attribute__((ext_vector_type(8)));
typedef __bf16 bf16x4 __attribute__((ext_vector_type(4)));
typedef float  f32x4  __attribute__((ext_vector_type(4)));

__device__ __forceinline__ float sigf(float x) { return 1.0f / (1.0f + __expf(-x)); }

__device__ __forceinline__ bf16x4 cvt4(f32x4 v) {
    bf16x4 r;
    r[0] = (__bf16)v[0]; r[1] = (__bf16)v[1];
    r[2] = (__bf16)v[2]; r[3] = (__bf16)v[3];
    return r;
}

__device__ __forceinline__ void glds16(const __bf16* g, __bf16* l) {
    __builtin_amdgcn_global_load_lds(
        (const __attribute__((address_space(1))) void*)g,
        (__attribute__((address_space(3))) void*)l, 16, 0, 0);
}

template<int N> __device__ __forceinline__ void waitvm();
template<> __device__ __forceinline__ void waitvm<0>() { asm volatile("s_waitcnt vmcnt(0)" ::: "memory"); }
template<> __device__ __forceinline__ void waitvm<4>() { asm volatile("s_waitcnt vmcnt(4)" ::: "memory"); }
template<> __device__ __forceinline__ void waitvm<6>() { asm volatile("s_waitcnt vmcnt(6)" ::: "memory"); }

#define BAR   __builtin_amdgcn_s_barrier()
#define SB0   __builtin_amdgcn_sched_barrier(0)
#define LGKM0 asm volatile("s_waitcnt lgkmcnt(0)" ::: "memory")
#define MEMF  asm volatile("" ::: "memory")

// ===================== prepass: X, S, weights -> bf16 =====================
// ws elems: [0) Xb 8388608 | [8388608) Sb 8388608 | [16777216) weights:
//   +0 Wzw 512x1024 | +524288 Wh' 512x512 | +786432 Wzc 512x1024 | +1310720 Wit 512x512
__global__ __launch_bounds__(256)
void petnn_cvt(const float* __restrict__ X,   const float* __restrict__ S,
               const float* __restrict__ Wzw, const float* __restrict__ Wh,
               const float* __restrict__ Wzc, const float* __restrict__ Wit,
               __bf16* __restrict__ ws)
{
    const int i = blockIdx.x * 256 + threadIdx.x;   // f32x4 chunk, 4587520 total
    const float* src; size_t dst;
    if (i < 2097152)      { src = X + (size_t)i * 4; dst = (size_t)i * 4; }
    else if (i < 4194304) { const int j = i - 2097152;
                            src = S + (size_t)j * 4; dst = 8388608 + (size_t)j * 4; }
    else {
        const int j = i - 4194304;                  // 0..393215 (weights)
        if (j < 131072)      { src = Wzw + (size_t)j * 4;
                               dst = 16777216 + (size_t)j * 4; }
        else if (j < 196608) { const int jj = j - 131072;   // Wh cols 0..511
                               src = Wh + (size_t)(jj >> 7) * 1024 + (jj & 127) * 4;
                               dst = 16777216 + 524288 + (size_t)jj * 4; }
        else if (j < 327680) { const int jj = j - 196608;
                               src = Wzc + (size_t)jj * 4;
                               dst = 16777216 + 786432 + (size_t)jj * 4; }
        else                 { const int jj = j - 327680;
                               src = Wit + (size_t)jj * 4;
                               dst = 16777216 + 1310720 + (size_t)jj * 4; }
    }
    *(bf16x4*)(ws + dst) = cvt4(*(const f32x4*)src);
}

// ===================== main: m201-ordered 3-buffer pipeline =====================
// BM=128 x BN=128 (P||Q), BK=64, 16 K-tiles (Q only kt<8). 512 thr = 8 waves
// 2(M) x 4(N); wave tile 64x32 per output; acc 64 regs/thread.
// LDS: sA 3x16K + sB 3x32K = 144 KiB (3-deep pipeline, prefetch dist 2).
__global__ __launch_bounds__(512, 2)
void petnn_fused8(const __bf16* __restrict__ Xb, const __bf16* __restrict__ Sb,
                  const __bf16* __restrict__ wb,
                  const float* __restrict__ bzw, const float* __restrict__ bh,
                  const float* __restrict__ bzc, const float* __restrict__ bit_,
                  float* __restrict__ out)
{
    __shared__ __align__(16) __bf16 sA[3 * 128 * 64];        // 48 KiB
    __shared__ __align__(16) __bf16 sB[3 * 2 * 128 * 64];    // 96 KiB [buf][P/Q][c][k]

    const int tid = threadIdx.x;
    const int bid = blockIdx.x;
    // XCD-chunked swizzle (1024 wgs, bijective; HW XCD = bid & 7): per XCD
    // 16 mblk x (4 nblk x 2 fam) consecutive -> A panel shared 8x in L2.
    const int orig = (bid & 7) * 128 + (bid >> 3);
    const int fam  = orig & 1;
    const int nblk = (orig >> 1) & 3;
    const int mblk = orig >> 3;            // 0..127

    const int lane = tid & 63, wid = tid >> 6;
    const int wm = wid >> 2;               // 0..1 (64-row half of 128)
    const int wn = wid & 3;                // 0..3 (32-col slice of 128)
    const int l15 = lane & 15;
    const int kq  = (lane >> 4) * 8;

    const int arow0 = mblk * 128;
    const int ncol0 = nblk * 128;

    // staging sources (XOR swizzle baked into GLOBAL addr; LDS dest linear):
    // thread t stages row/col (t>>3) of each 64-row group, chunk (t&7).
    const int gr   = tid >> 3;             // 0..63
    const int gswz = ((tid & 7) ^ (gr & 7)) << 3;
    const __bf16* pXA = Xb + (size_t)(arow0 + gr) * 512 + gswz;
    const __bf16* pSA = Sb + (size_t)(arow0 + gr) * 512 + gswz;
    const __bf16* wbase = wb + (size_t)fam * 786432;
    const __bf16* pP = wbase + (size_t)(ncol0 + gr) * 1024 + gswz;           // K=1024
    const __bf16* pQ = wbase + 524288 + (size_t)(ncol0 + gr) * 512 + gswz;   // K=512

    // fragment read offsets (elems within one buffer slot)
    int aoff[2][4], boff[2][2];
    #pragma unroll
    for (int f = 0; f < 4; ++f) {
        const int r = wm * 64 + f * 16 + l15;
        aoff[0][f] = r * 64 + (kq        ^ ((r & 7) * 8));
        aoff[1][f] = r * 64 + ((32 + kq) ^ ((r & 7) * 8));
    }
    #pragma unroll
    for (int f = 0; f < 2; ++f) {
        const int c = wn * 32 + f * 16 + l15;
        boff[0][f] = c * 64 + (kq        ^ ((c & 7) * 8));
        boff[1][f] = c * 64 + ((32 + kq) ^ ((c & 7) * 8));
    }

    f32x4 accP[4][2] = {}, accQ[4][2] = {};

    // issue units (2 glds = 16 KiB each); buffer slot = T % 3
#define ISSUE_A(T) if ((T) < 16) { \
        const __bf16* ab_ = ((T) < 8) ? pXA : pSA; \
        const int kg_ = ((T) & 7) * 64; \
        __bf16* d_ = sA + ((T) % 3) * 8192 + tid * 8; \
        glds16(ab_ + kg_, d_); \
        glds16(ab_ + 64 * 512 + kg_, d_ + 4096); }
#define ISSUE_P(T) if ((T) < 16) { \
        __bf16* d_ = sB + ((T) % 3) * 16384 + tid * 8; \
        glds16(pP + (T) * 64, d_); \
        glds16(pP + 64 * 1024 + (T) * 64, d_ + 4096); }
#define ISSUE_Q(T) if ((T) < 8) { \
        __bf16* d_ = sB + ((T) % 3) * 16384 + 8192 + tid * 8; \
        glds16(pQ + (T) * 64, d_); \
        glds16(pQ + 64 * 512 + (T) * 64, d_ + 4096); }

    // one phase (m201 ordering): reads -> glds issue -> [vm wait] -> BAR ->
    // lgkm0+SB0 -> prio-wrapped MFMA cluster -> BAR.
#define PHASE(T, KK, FULL_, DOISS, ISSA, W) { \
        const __bf16* aS_ = sA + ((T) % 3) * 8192; \
        const __bf16* bS_ = sB + ((T) % 3) * 16384; \
        bf16x8 af[4], bp[2], bq[2]; \
        _Pragma("unroll") \
        for (int f = 0; f < 4; ++f) af[f] = *(const bf16x8*)(aS_ + aoff[KK][f]); \
        _Pragma("unroll") \
        for (int f = 0; f < 2; ++f) bp[f] = *(const bf16x8*)(bS_ + boff[KK][f]); \
        if (FULL_) { \
            _Pragma("unroll") \
            for (int f = 0; f < 2; ++f) bq[f] = *(const bf16x8*)(bS_ + 8192 + boff[KK][f]); \
        } \
        if (DOISS) { \
            if (ISSA) { ISSUE_A((T) + 2) } \
            else      { ISSUE_P((T) + 2) ISSUE_Q((T) + 2) } \
        } \
        if ((W) >= 0) { \
            if ((W) == 6) waitvm<6>(); else if ((W) == 4) waitvm<4>(); else waitvm<0>(); \
        } \
        MEMF; BAR; \
        LGKM0; SB0; \
        __builtin_amdgcn_s_setprio(1); \
        _Pragma("unroll") \
        for (int nf = 0; nf < 2; ++nf) \
            _Pragma("unroll") \
            for (int mf = 0; mf < 4; ++mf) \
                accP[mf][nf] = __builtin_amdgcn_mfma_f32_16x16x32_bf16(af[mf], bp[nf], accP[mf][nf], 0, 0, 0); \
        if (FULL_) { \
            _Pragma("unroll") \
            for (int nf = 0; nf < 2; ++nf) \
                _Pragma("unroll") \
                for (int mf = 0; mf < 4; ++mf) \
                    accQ[mf][nf] = __builtin_amdgcn_mfma_f32_16x16x32_bf16(af[mf], bq[nf], accQ[mf][nf], 0, 0, 0); \
        } \
        __builtin_amdgcn_s_setprio(0); \
        MEMF; BAR; }

    // STEP(T): ph0 issues A(T+2); ph1 issues P/Q(T+2) then counted wait W
    // (waits tile T+1's units, leaves T+2's in flight; never 0 until T>=14).
#define STEP(T, W) \
        PHASE(T, 0, (T) < 8, 1, 1, -1) \
        PHASE(T, 1, (T) < 8, 1, 0, W)

    // prologue: tiles 0 and 1 fully issued; wait tile 0 (leave tile 1 in flight)
    ISSUE_A(0) ISSUE_P(0) ISSUE_Q(0)
    ISSUE_A(1) ISSUE_P(1) ISSUE_Q(1)
    waitvm<6>(); MEMF; BAR;

    STEP(0, 6)  STEP(1, 6)  STEP(2, 6)  STEP(3, 6)
    STEP(4, 6)  STEP(5, 6)  STEP(6, 4)  STEP(7, 4)
    STEP(8, 4)  STEP(9, 4)  STEP(10, 4) STEP(11, 4)
    STEP(12, 4) STEP(13, 4) STEP(14, 0) STEP(15, 0)

#undef STEP
#undef PHASE
#undef ISSUE_A
#undef ISSUE_P
#undef ISSUE_Q

    // ---- fused epilogue ----
    // C/D frag layout (m89/m91): col = lane&15, row = (lane>>4)*4 + reg
    const int rowb = arow0 + wm * 64;
    const int colb = ncol0 + wn * 32;
    if (fam == 0) {
        #pragma unroll
        for (int nf = 0; nf < 2; ++nf) {
            const int col = colb + nf * 16 + l15;
            const float vzw = bzw[col], vh = bh[col];
            #pragma unroll
            for (int mf = 0; mf < 4; ++mf) {
                #pragma unroll
                for (int j = 0; j < 4; ++j) {
                    const int row = rowb + mf * 16 + ((lane >> 4) << 2) + j;
                    const size_t off = (size_t)row * DDIM + col;
                    const float zw = sigf(accP[mf][nf][j] + vzw);
                    const float hh = sigf(accQ[mf][nf][j] + vh);
                    out[off] = sigf((1.0f - zw) * (float)Sb[off] + zw * hh
                                    + (float)Xb[off]);                 // S_new
                }
            }
        }
    } else {
        #pragma unroll
        for (int nf = 0; nf < 2; ++nf) {
            const int col = colb + nf * 16 + l15;
            const float vzc = bzc[col], vit = bit_[col];
            #pragma unroll
            for (int mf = 0; mf < 4; ++mf) {
                #pragma unroll
                for (int j = 0; j < 4; ++j) {
                    const int row = rowb + mf * 16 + ((lane >> 4) << 2) + j;
                    const size_t off = (size_t)row * DDIM + col;
                    out[(size_t)BROWS * DDIM + off] =
                        (accP[mf][nf][j] + vzc) + (accQ[mf][nf][j] + vit); // C_new
                }
            }
        }
    }
}

// ===================== fallback (ws too small): R4 path =====================
__global__ __launch_bounds__(256)
void petnn_cvtw(const float* __restrict__ Wzw, const float* __restrict__ Wh,
                const float* __restrict__ Wzc, const float* __restrict__ Wit,
                __bf16* __restrict__ wb)
{
    const int i = blockIdx.x * 256 + threadIdx.x;
    const float* src; size_t dst;
    if (i < 131072)      { src = Wzw + (size_t)i * 4;  dst = (size_t)i * 4; }
    else if (i < 196608) { const int j = i - 131072;
                           src = Wh + (size_t)(j >> 7) * 1024 + (j & 127) * 4;
                           dst = 524288 + (size_t)j * 4; }
    else if (i < 327680) { const int j = i - 196608;
                           src = Wzc + (size_t)j * 4;  dst = 786432 + (size_t)j * 4; }
    else                 { const int j = i - 327680;
                           src = Wit + (size_t)j * 4;  dst = 1310720 + (size_t)j * 4; }
    *(bf16x4*)(wb + dst) = cvt4(*(const f32x4*)src);
}

__global__ __launch_bounds__(512, 4)
void petnn_fused(const float* __restrict__ X,   const float* __restrict__ S,
                 const __bf16* __restrict__ wb,
                 const float* __restrict__ bzw, const float* __restrict__ bh,
                 const float* __restrict__ bzc, const float* __restrict__ bit_,
                 float* __restrict__ out)
{
    __shared__ __align__(16) __bf16 sA[128 * 64];
    __shared__ __align__(16) __bf16 sB[2 * 2 * 64 * 64];

    const int tid = threadIdx.x;
    const int bid = blockIdx.x;
    const int orig = (bid & 7) * 256 + (bid >> 3);
    const int fam  = orig & 1;
    const int nblk = (orig >> 1) & 7;
    const int mblk = orig >> 4;
    const int lane = tid & 63, wid = tid >> 6;
    const int wm = wid >> 2, wn = wid & 3;
    const int arow0 = mblk * 128, ncol0 = nblk * 64;
    const int srow = tid >> 4, skq = (tid & 15) << 2;
    const int bn = tid >> 3;
    const int bks = ((tid & 7) ^ (bn & 7)) << 3;
    const __bf16* wP = wb + (size_t)fam * 786432 + (size_t)(ncol0 + bn) * 1024 + bks;
    const __bf16* wQ = wb + (size_t)fam * 786432 + 524288 + (size_t)(ncol0 + bn) * 512 + bks;
    __bf16* ldsB = sB + tid * 8;

    f32x4 aP[4] = {}, aQ[4] = {};
    f32x4 ra[4];

    glds16(wP, ldsB);
    glds16(wQ, ldsB + 4096);
    #pragma unroll
    for (int p = 0; p < 4; ++p)
        ra[p] = *(const f32x4*)(X + (size_t)(arow0 + p * 32 + srow) * DDIM + skq);
    glds16(wP + 64, ldsB + 8192);
    glds16(wQ + 64, ldsB + 8192 + 4096);

    for (int kt = 0; kt < 16; ++kt) {
        const bool full = kt < 8;
        #pragma unroll
        for (int p = 0; p < 4; ++p) {
            const int r = p * 32 + srow;
            *(bf16x4*)(sA + r * 64 + (skq ^ ((r & 7) * 8))) = cvt4(ra[p]);
        }
        if (kt + 1 < 16) {
            const float* asrc = (kt + 1 < 8) ? X : S;
            const int kga = ((kt + 1) & 7) * 64 + skq;
            #pragma unroll
            for (int p = 0; p < 4; ++p)
                ra[p] = *(const f32x4*)(asrc + (size_t)(arow0 + p * 32 + srow) * DDIM + kga);
        }
        asm volatile("s_waitcnt lgkmcnt(0)" ::: "memory");
        __builtin_amdgcn_s_barrier();

        const __bf16* bb = sB + (kt & 1) * 8192;
        #pragma unroll
        for (int kk = 0; kk < 2; ++kk) {
            const int kbe = kk * 32 + (lane >> 4) * 8;
            bf16x8 af[4];
            #pragma unroll
            for (int mf = 0; mf < 4; ++mf) {
                const int r = wm * 64 + mf * 16 + (lane & 15);
                af[mf] = *(const bf16x8*)(sA + r * 64 + (kbe ^ ((r & 7) * 8)));
            }
            const int nr = wn * 16 + (lane & 15);
            const int sx = nr * 64 + (kbe ^ ((nr & 7) * 8));
            const bf16x8 bP = *(const bf16x8*)(bb + sx);
            #pragma unroll
            for (int mf = 0; mf < 4; ++mf)
                aP[mf] = __builtin_amdgcn_mfma_f32_16x16x32_bf16(af[mf], bP, aP[mf], 0, 0, 0);
            if (full) {
                const bf16x8 bQ = *(const bf16x8*)(bb + 4096 + sx);
                #pragma unroll
                for (int mf = 0; mf < 4; ++mf)
                    aQ[mf] = __builtin_amdgcn_mfma_f32_16x16x32_bf16(af[mf], bQ, aQ[mf], 0, 0, 0);
            }
        }

        if (kt + 1 < 16) {
            asm volatile("" ::: "memory");
            __builtin_amdgcn_s_barrier();
            asm volatile("" ::: "memory");
            if (kt + 2 < 16) {
                __bf16* bd = sB + (kt & 1) * 8192 + tid * 8;
                glds16(wP + (size_t)(kt + 2) * 64, bd);
                if (kt + 2 < 8) glds16(wQ + (size_t)(kt + 2) * 64, bd + 4096);
            }
        }
    }

    const int col  = ncol0 + wn * 16 + (lane & 15);
    const int rowb = arow0 + wm * 64;
    if (fam == 0) {
        const float vzw = bzw[col], vh = bh[col];
        #pragma unroll
        for (int mf = 0; mf < 4; ++mf) {
            #pragma unroll
            for (int j = 0; j < 4; ++j) {
                const int row = rowb + mf * 16 + ((lane >> 4) << 2) + j;
                const size_t off = (size_t)row * DDIM + col;
                const float zw = sigf(aP[mf][j] + vzw);
                const float hh = sigf(aQ[mf][j] + vh);
                out[off] = sigf((1.0f - zw) * S[off] + zw * hh + X[off]);
            }
        }
    } else {
        const float vzc = bzc[col], vit = bit_[col];
        #pragma unroll
        for (int mf = 0; mf < 4; ++mf) {
            #pragma unroll
            for (int j = 0; j < 4; ++j) {
                const int row = rowb + mf * 16 + ((lane >> 4) << 2) + j;
                const size_t off = (size_t)row * DDIM + col;
                out[(size_t)BROWS * DDIM + off] =
                    (aP[mf][j] + vzc) + (aQ[mf][j] + vit);
            }
        }
    }
}

__global__ void petnn_zeroT(float* __restrict__ t) {
    t[blockIdx.x * 256 + threadIdx.x] = 0.0f;   // T_t == 0 exactly
}

extern "C" void kernel_launch(void* const* d_in, const int* in_sizes, int n_in,
                              void* d_out, int out_size, void* d_ws, size_t ws_size,
                              hipStream_t stream) {
    (void)in_sizes; (void)n_in; (void)out_size;
    const float* X    = (const float*)d_in[0];
    const float* S    = (const float*)d_in[1];
    const float* Wzc  = (const float*)d_in[6];
    const float* bzc  = (const float*)d_in[7];
    const float* Wzw  = (const float*)d_in[8];
    const float* bzw  = (const float*)d_in[9];
    const float* Wit  = (const float*)d_in[10];
    const float* bit_ = (const float*)d_in[11];
    const float* Wh   = (const float*)d_in[14];
    const float* bh   = (const float*)d_in[15];
    float* out = (float*)d_out;

    if (ws_size >= 36700160u) {
        __bf16* ws = (__bf16*)d_ws;
        const __bf16* Xb = ws;
        const __bf16* Sb = ws + 8388608;
        const __bf16* wb = ws + 16777216;
        petnn_cvt<<<dim3(17920), dim3(256), 0, stream>>>(X, S, Wzw, Wh, Wzc, Wit, ws);
        petnn_fused8<<<dim3(1024), dim3(512), 0, stream>>>(
            Xb, Sb, wb, bzw, bh, bzc, bit_, out);
    } else {
        __bf16* wb = (__bf16*)d_ws;
        petnn_cvtw<<<dim3(1536), dim3(256), 0, stream>>>(Wzw, Wh, Wzc, Wit, wb);
        petnn_fused<<<dim3(2048), dim3(512), 0, stream>>>(
            X, S, wb, bzw, bh, bzc, bit_, out);
    }
    petnn_zeroT<<<dim3(64), dim3(256), 0, stream>>>(out + 2 * (size_t)BROWS * DDIM);
}

// Round 12
// 111.916 us; speedup vs baseline: 1.0171x; 1.0171x over previous
//
#include <hip/hip_runtime.h>
#include <stdint.h>

// PETNNCell collapse (proven analytically):
//   T_t == 0, m == 1;  C_new = I_t + Z_c;  h = sigmoid(X @ W_h[:, :512]^T + b_h)
//   S_new = sigmoid((1 - Z_w)*S_prev + Z_w*h + X)
//
// R12: unified diagnosis of the R5-R11 plateau (12-14 cyc/MFMA everywhere):
// every round either saturated the register file exactly (R9: 124+128acc =
// 252/256 -> compiler cannot double-buffer fragments -> reads serialize
// against MFMA) or over-pinned the scheduler (R11: SB0+LGKM0 per phase).
// Fix: R9's clean unpinned 1-barrier-per-tile loop + register-light tile
// (wave 64x32/output, acc 64, ~80 spare VGPRs) + explicit kk0/kk1 fragment
// sets so the compiler hoists kk1 reads under kk0 MFMAs via counted lgkmcnt.
// NO sched_barrier / NO lgkmcnt(0) in the loop body.

#define BROWS 16384
#define DDIM  512

typedef __bf16 bf16x8 __attribute__((ext_vector_type(8)));
typedef __bf16 bf16x4 __attribute__((ext_vector_type(4)));
typedef float  f32x4  __attribute__((ext_vector_type(4)));

__device__ __forceinline__ float sigf(float x) { return 1.0f / (1.0f + __expf(-x)); }

__device__ __forceinline__ bf16x4 cvt4(f32x4 v) {
    bf16x4 r;
    r[0] = (__bf16)v[0]; r[1] = (__bf16)v[1];
    r[2] = (__bf16)v[2]; r[3] = (__bf16)v[3];
    return r;
}

__device__ __forceinline__ void glds16(const __bf16* g, __bf16* l) {
    __builtin_amdgcn_global_load_lds(
        (const __attribute__((address_space(1))) void*)g,
        (__attribute__((address_space(3))) void*)l, 16, 0, 0);
}

#define BAR   __builtin_amdgcn_s_barrier()
#define VM0   asm volatile("s_waitcnt vmcnt(0)" ::: "memory")
#define MEMF  asm volatile("" ::: "memory")

// ===================== prepass: X, S, weights -> bf16 =====================
// ws elems: [0) Xb 8388608 | [8388608) Sb 8388608 | [16777216) weights:
//   +0 Wzw 512x1024 | +524288 Wh' 512x512 | +786432 Wzc 512x1024 | +1310720 Wit 512x512
__global__ __launch_bounds__(256)
void petnn_cvt(const float* __restrict__ X,   const float* __restrict__ S,
               const float* __restrict__ Wzw, const float* __restrict__ Wh,
               const float* __restrict__ Wzc, const float* __restrict__ Wit,
               __bf16* __restrict__ ws)
{
    const int i = blockIdx.x * 256 + threadIdx.x;   // f32x4 chunk, 4587520 total
    const float* src; size_t dst;
    if (i < 2097152)      { src = X + (size_t)i * 4; dst = (size_t)i * 4; }
    else if (i < 4194304) { const int j = i - 2097152;
                            src = S + (size_t)j * 4; dst = 8388608 + (size_t)j * 4; }
    else {
        const int j = i - 4194304;                  // 0..393215 (weights)
        if (j < 131072)      { src = Wzw + (size_t)j * 4;
                               dst = 16777216 + (size_t)j * 4; }
        else if (j < 196608) { const int jj = j - 131072;   // Wh cols 0..511
                               src = Wh + (size_t)(jj >> 7) * 1024 + (jj & 127) * 4;
                               dst = 16777216 + 524288 + (size_t)jj * 4; }
        else if (j < 327680) { const int jj = j - 196608;
                               src = Wzc + (size_t)jj * 4;
                               dst = 16777216 + 786432 + (size_t)jj * 4; }
        else                 { const int jj = j - 327680;
                               src = Wit + (size_t)jj * 4;
                               dst = 16777216 + 1310720 + (size_t)jj * 4; }
    }
    *(bf16x4*)(ws + dst) = cvt4(*(const f32x4*)src);
}

// ===================== main: unpinned loop, register-light tile =====================
// BM=128 x BN=128 (P||Q), BK=64, 16 K-tiles (Q only kt<8). 512 thr = 8 waves
// 2(M) x 4(N); wave tile 64x32 per output; acc 64 regs/thread (~80 spare).
// LDS: sA 2x16K + sB 2x32K = 96 KiB (2-deep), 1 block/CU.
__global__ __launch_bounds__(512, 2)
void petnn_fused9(const __bf16* __restrict__ Xb, const __bf16* __restrict__ Sb,
                  const __bf16* __restrict__ wb,
                  const float* __restrict__ bzw, const float* __restrict__ bh,
                  const float* __restrict__ bzc, const float* __restrict__ bit_,
                  float* __restrict__ out)
{
    __shared__ __align__(16) __bf16 sA[2 * 128 * 64];        // 32 KiB
    __shared__ __align__(16) __bf16 sB[2 * 2 * 128 * 64];    // 64 KiB [buf][P/Q][c][k]

    const int tid = threadIdx.x;
    const int bid = blockIdx.x;
    // XCD-chunked swizzle (1024 wgs, bijective; HW XCD = bid & 7): per XCD
    // 16 mblk x (4 nblk x 2 fam) consecutive -> A panel shared 8x in L2.
    const int orig = (bid & 7) * 128 + (bid >> 3);
    const int fam  = orig & 1;
    const int nblk = (orig >> 1) & 3;
    const int mblk = orig >> 3;            // 0..127

    const int lane = tid & 63, wid = tid >> 6;
    const int wm = wid >> 2;               // 0..1 (64-row half of 128)
    const int wn = wid & 3;                // 0..3 (32-col slice of 128)
    const int l15 = lane & 15;
    const int kq  = (lane >> 4) * 8;

    const int arow0 = mblk * 128;
    const int ncol0 = nblk * 128;

    // staging sources (XOR swizzle baked into GLOBAL addr; LDS dest linear):
    // thread t stages row/col (t>>3) of each 64-row group, chunk (t&7).
    const int gr   = tid >> 3;             // 0..63
    const int gswz = ((tid & 7) ^ (gr & 7)) << 3;
    const __bf16* pXA = Xb + (size_t)(arow0 + gr) * 512 + gswz;
    const __bf16* pSA = Sb + (size_t)(arow0 + gr) * 512 + gswz;
    const __bf16* wbase = wb + (size_t)fam * 786432;
    const __bf16* pP = wbase + (size_t)(ncol0 + gr) * 1024 + gswz;           // K=1024
    const __bf16* pQ = wbase + 524288 + (size_t)(ncol0 + gr) * 512 + gswz;   // K=512

    // fragment read offsets (elems within one buffer slot)
    int aoff[2][4], boff[2][2];
    #pragma unroll
    for (int f = 0; f < 4; ++f) {
        const int r = wm * 64 + f * 16 + l15;
        aoff[0][f] = r * 64 + (kq        ^ ((r & 7) * 8));
        aoff[1][f] = r * 64 + ((32 + kq) ^ ((r & 7) * 8));
    }
    #pragma unroll
    for (int f = 0; f < 2; ++f) {
        const int c = wn * 32 + f * 16 + l15;
        boff[0][f] = c * 64 + (kq        ^ ((c & 7) * 8));
        boff[1][f] = c * 64 + ((32 + kq) ^ ((c & 7) * 8));
    }

    f32x4 accP[4][2] = {}, accQ[4][2] = {};

    // tile T staging: 6 units (12 loads) full, 4 units (8) tail
#define ISSUE_T(T) if ((T) < 16) { \
        const __bf16* ab_ = ((T) < 8) ? pXA : pSA; \
        const int kg_ = ((T) & 7) * 64; \
        __bf16* dA_ = sA + ((T) & 1) * 8192 + tid * 8; \
        glds16(ab_ + kg_, dA_); \
        glds16(ab_ + 64 * 512 + kg_, dA_ + 4096); \
        __bf16* dB_ = sB + ((T) & 1) * 16384 + tid * 8; \
        glds16(pP + (T) * 64, dB_); \
        glds16(pP + 64 * 1024 + (T) * 64, dB_ + 4096); \
        if ((T) < 8) { \
            glds16(pQ + (T) * 64, dB_ + 8192); \
            glds16(pQ + 64 * 512 + (T) * 64, dB_ + 8192 + 4096); \
        } }

    // tile body: explicit kk0/kk1 fragment sets (named regs -> compiler
    // hoists kk1 reads under kk0 MFMAs with counted lgkmcnt). NO fences.
#define BODY(T) { \
        const __bf16* aS_ = sA + ((T) & 1) * 8192; \
        const __bf16* bS_ = sB + ((T) & 1) * 16384; \
        bf16x8 a0[4], a1[4], p0[2], p1[2]; \
        _Pragma("unroll") \
        for (int f = 0; f < 4; ++f) { \
            a0[f] = *(const bf16x8*)(aS_ + aoff[0][f]); \
            a1[f] = *(const bf16x8*)(aS_ + aoff[1][f]); \
        } \
        _Pragma("unroll") \
        for (int f = 0; f < 2; ++f) { \
            p0[f] = *(const bf16x8*)(bS_ + boff[0][f]); \
            p1[f] = *(const bf16x8*)(bS_ + boff[1][f]); \
        } \
        if ((T) < 8) { \
            bf16x8 q0[2], q1[2]; \
            _Pragma("unroll") \
            for (int f = 0; f < 2; ++f) { \
                q0[f] = *(const bf16x8*)(bS_ + 8192 + boff[0][f]); \
                q1[f] = *(const bf16x8*)(bS_ + 8192 + boff[1][f]); \
            } \
            __builtin_amdgcn_s_setprio(1); \
            _Pragma("unroll") \
            for (int nf = 0; nf < 2; ++nf) \
                _Pragma("unroll") \
                for (int mf = 0; mf < 4; ++mf) { \
                    accP[mf][nf] = __builtin_amdgcn_mfma_f32_16x16x32_bf16(a0[mf], p0[nf], accP[mf][nf], 0, 0, 0); \
                    accQ[mf][nf] = __builtin_amdgcn_mfma_f32_16x16x32_bf16(a0[mf], q0[nf], accQ[mf][nf], 0, 0, 0); \
                } \
            _Pragma("unroll") \
            for (int nf = 0; nf < 2; ++nf) \
                _Pragma("unroll") \
                for (int mf = 0; mf < 4; ++mf) { \
                    accP[mf][nf] = __builtin_amdgcn_mfma_f32_16x16x32_bf16(a1[mf], p1[nf], accP[mf][nf], 0, 0, 0); \
                    accQ[mf][nf] = __builtin_amdgcn_mfma_f32_16x16x32_bf16(a1[mf], q1[nf], accQ[mf][nf], 0, 0, 0); \
                } \
            __builtin_amdgcn_s_setprio(0); \
        } else { \
            __builtin_amdgcn_s_setprio(1); \
            _Pragma("unroll") \
            for (int nf = 0; nf < 2; ++nf) \
                _Pragma("unroll") \
                for (int mf = 0; mf < 4; ++mf) \
                    accP[mf][nf] = __builtin_amdgcn_mfma_f32_16x16x32_bf16(a0[mf], p0[nf], accP[mf][nf], 0, 0, 0); \
            _Pragma("unroll") \
            for (int nf = 0; nf < 2; ++nf) \
                _Pragma("unroll") \
                for (int mf = 0; mf < 4; ++mf) \
                    accP[mf][nf] = __builtin_amdgcn_mfma_f32_16x16x32_bf16(a1[mf], p1[nf], accP[mf][nf], 0, 0, 0); \
            __builtin_amdgcn_s_setprio(0); \
        } }

    // STEP(T): vmcnt(0) waits only tile T's loads (issued a full tile body
    // earlier). Single barrier publishes tile T AND certifies buf[(T+1)&1]
    // free (tile T-1 readers drained by MFMA operand waits before arrival).
#define STEP(T) { \
        VM0; MEMF; BAR; MEMF; \
        ISSUE_T((T) + 1) \
        MEMF; \
        BODY(T) }

    // prologue: tile 0 only
    ISSUE_T(0)

    STEP(0)  STEP(1)  STEP(2)  STEP(3)
    STEP(4)  STEP(5)  STEP(6)  STEP(7)
    STEP(8)  STEP(9)  STEP(10) STEP(11)
    STEP(12) STEP(13) STEP(14) STEP(15)

#undef STEP
#undef BODY
#undef ISSUE_T

    // ---- fused epilogue ----
    // C/D frag layout (m89/m91): col = lane&15, row = (lane>>4)*4 + reg
    const int rowb = arow0 + wm * 64;
    const int colb = ncol0 + wn * 32;
    if (fam == 0) {
        #pragma unroll
        for (int nf = 0; nf < 2; ++nf) {
            const int col = colb + nf * 16 + l15;
            const float vzw = bzw[col], vh = bh[col];
            #pragma unroll
            for (int mf = 0; mf < 4; ++mf) {
                #pragma unroll
                for (int j = 0; j < 4; ++j) {
                    const int row = rowb + mf * 16 + ((lane >> 4) << 2) + j;
                    const size_t off = (size_t)row * DDIM + col;
                    const float zw = sigf(accP[mf][nf][j] + vzw);
                    const float hh = sigf(accQ[mf][nf][j] + vh);
                    out[off] = sigf((1.0f - zw) * (float)Sb[off] + zw * hh
                                    + (float)Xb[off]);                 // S_new
                }
            }
        }
    } else {
        #pragma unroll
        for (int nf = 0; nf < 2; ++nf) {
            const int col = colb + nf * 16 + l15;
            const float vzc = bzc[col], vit = bit_[col];
            #pragma unroll
            for (int mf = 0; mf < 4; ++mf) {
                #pragma unroll
                for (int j = 0; j < 4; ++j) {
                    const int row = rowb + mf * 16 + ((lane >> 4) << 2) + j;
                    const size_t off = (size_t)row * DDIM + col;
                    out[(size_t)BROWS * DDIM + off] =
                        (accP[mf][nf][j] + vzc) + (accQ[mf][nf][j] + vit); // C_new
                }
            }
        }
    }
}

// ===================== fallback (ws too small): R4 path =====================
__global__ __launch_bounds__(256)
void petnn_cvtw(const float* __restrict__ Wzw, const float* __restrict__ Wh,
                const float* __restrict__ Wzc, const float* __restrict__ Wit,
                __bf16* __restrict__ wb)
{
    const int i = blockIdx.x * 256 + threadIdx.x;
    const float* src; size_t dst;
    if (i < 131072)      { src = Wzw + (size_t)i * 4;  dst = (size_t)i * 4; }
    else if (i < 196608) { const int j = i - 131072;
                           src = Wh + (size_t)(j >> 7) * 1024 + (j & 127) * 4;
                           dst = 524288 + (size_t)j * 4; }
    else if (i < 327680) { const int j = i - 196608;
                           src = Wzc + (size_t)j * 4;  dst = 786432 + (size_t)j * 4; }
    else                 { const int j = i - 327680;
                           src = Wit + (size_t)j * 4;  dst = 1310720 + (size_t)j * 4; }
    *(bf16x4*)(wb + dst) = cvt4(*(const f32x4*)src);
}

__global__ __launch_bounds__(512, 4)
void petnn_fused(const float* __restrict__ X,   const float* __restrict__ S,
                 const __bf16* __restrict__ wb,
                 const float* __restrict__ bzw, const float* __restrict__ bh,
                 const float* __restrict__ bzc, const float* __restrict__ bit_,
                 float* __restrict__ out)
{
    __shared__ __align__(16) __bf16 sA[128 * 64];
    __shared__ __align__(16) __bf16 sB[2 * 2 * 64 * 64];

    const int tid = threadIdx.x;
    const int bid = blockIdx.x;
    const int orig = (bid & 7) * 256 + (bid >> 3);
    const int fam  = orig & 1;
    const int nblk = (orig >> 1) & 7;
    const int mblk = orig >> 4;
    const int lane = tid & 63, wid = tid >> 6;
    const int wm = wid >> 2, wn = wid & 3;
    const int arow0 = mblk * 128, ncol0 = nblk * 64;
    const int srow = tid >> 4, skq = (tid & 15) << 2;
    const int bn = tid >> 3;
    const int bks = ((tid & 7) ^ (bn & 7)) << 3;
    const __bf16* wP = wb + (size_t)fam * 786432 + (size_t)(ncol0 + bn) * 1024 + bks;
    const __bf16* wQ = wb + (size_t)fam * 786432 + 524288 + (size_t)(ncol0 + bn) * 512 + bks;
    __bf16* ldsB = sB + tid * 8;

    f32x4 aP[4] = {}, aQ[4] = {};
    f32x4 ra[4];

    glds16(wP, ldsB);
    glds16(wQ, ldsB + 4096);
    #pragma unroll
    for (int p = 0; p < 4; ++p)
        ra[p] = *(const f32x4*)(X + (size_t)(arow0 + p * 32 + srow) * DDIM + skq);
    glds16(wP + 64, ldsB + 8192);
    glds16(wQ + 64, ldsB + 8192 + 4096);

    for (int kt = 0; kt < 16; ++kt) {
        const bool full = kt < 8;
        #pragma unroll
        for (int p = 0; p < 4; ++p) {
            const int r = p * 32 + srow;
            *(bf16x4*)(sA + r * 64 + (skq ^ ((r & 7) * 8))) = cvt4(ra[p]);
        }
        if (kt + 1 < 16) {
            const float* asrc = (kt + 1 < 8) ? X : S;
            const int kga = ((kt + 1) & 7) * 64 + skq;
            #pragma unroll
            for (int p = 0; p < 4; ++p)
                ra[p] = *(const f32x4*)(asrc + (size_t)(arow0 + p * 32 + srow) * DDIM + kga);
        }
        asm volatile("s_waitcnt lgkmcnt(0)" ::: "memory");
        __builtin_amdgcn_s_barrier();

        const __bf16* bb = sB + (kt & 1) * 8192;
        #pragma unroll
        for (int kk = 0; kk < 2; ++kk) {
            const int kbe = kk * 32 + (lane >> 4) * 8;
            bf16x8 af[4];
            #pragma unroll
            for (int mf = 0; mf < 4; ++mf) {
                const int r = wm * 64 + mf * 16 + (lane & 15);
                af[mf] = *(const bf16x8*)(sA + r * 64 + (kbe ^ ((r & 7) * 8)));
            }
            const int nr = wn * 16 + (lane & 15);
            const int sx = nr * 64 + (kbe ^ ((nr & 7) * 8));
            const bf16x8 bP = *(const bf16x8*)(bb + sx);
            #pragma unroll
            for (int mf = 0; mf < 4; ++mf)
                aP[mf] = __builtin_amdgcn_mfma_f32_16x16x32_bf16(af[mf], bP, aP[mf], 0, 0, 0);
            if (full) {
                const bf16x8 bQ = *(const bf16x8*)(bb + 4096 + sx);
                #pragma unroll
                for (int mf = 0; mf < 4; ++mf)
                    aQ[mf] = __builtin_amdgcn_mfma_f32_16x16x32_bf16(af[mf], bQ, aQ[mf], 0, 0, 0);
            }
        }

        if (kt + 1 < 16) {
            asm volatile("" ::: "memory");
            __builtin_amdgcn_s_barrier();
            asm volatile("" ::: "memory");
            if (kt + 2 < 16) {
                __bf16* bd = sB + (kt & 1) * 8192 + tid * 8;
                glds16(wP + (size_t)(kt + 2) * 64, bd);
                if (kt + 2 < 8) glds16(wQ + (size_t)(kt + 2) * 64, bd + 4096);
            }
        }
    }

    const int col  = ncol0 + wn * 16 + (lane & 15);
    const int rowb = arow0 + wm * 64;
    if (fam == 0) {
        const float vzw = bzw[col], vh = bh[col];
        #pragma unroll
        for (int mf = 0; mf < 4; ++mf) {
            #pragma unroll
            for (int j = 0; j < 4; ++j) {
                const int row = rowb + mf * 16 + ((lane >> 4) << 2) + j;
                const size_t off = (size_t)row * DDIM + col;
                const float zw = sigf(aP[mf][j] + vzw);
                const float hh = sigf(aQ[mf][j] + vh);
                out[off] = sigf((1.0f - zw) * S[off] + zw * hh + X[off]);
            }
        }
    } else {
        const float vzc = bzc[col], vit = bit_[col];
        #pragma unroll
        for (int mf = 0; mf < 4; ++mf) {
            #pragma unroll
            for (int j = 0; j < 4; ++j) {
                const int row = rowb + mf * 16 + ((lane >> 4) << 2) + j;
                const size_t off = (size_t)row * DDIM + col;
                out[(size_t)BROWS * DDIM + off] =
                    (aP[mf][j] + vzc) + (aQ[mf][j] + vit);
            }
        }
    }
}

__global__ void petnn_zeroT(float* __restrict__ t) {
    t[blockIdx.x * 256 + threadIdx.x] = 0.0f;   // T_t == 0 exactly
}

extern "C" void kernel_launch(void* const* d_in, const int* in_sizes, int n_in,
                              void* d_out, int out_size, void* d_ws, size_t ws_size,
                              hipStream_t stream) {
    (void)in_sizes; (void)n_in; (void)out_size;
    const float* X    = (const float*)d_in[0];
    const float* S    = (const float*)d_in[1];
    const float* Wzc  = (const float*)d_in[6];
    const float* bzc  = (const float*)d_in[7];
    const float* Wzw  = (const float*)d_in[8];
    const float* bzw  = (const float*)d_in[9];
    const float* Wit  = (const float*)d_in[10];
    const float* bit_ = (const float*)d_in[11];
    const float* Wh   = (const float*)d_in[14];
    const float* bh   = (const float*)d_in[15];
    float* out = (float*)d_out;

    if (ws_size >= 36700160u) {
        __bf16* ws = (__bf16*)d_ws;
        const __bf16* Xb = ws;
        const __bf16* Sb = ws + 8388608;
        const __bf16* wb = ws + 16777216;
        petnn_cvt<<<dim3(17920), dim3(256), 0, stream>>>(X, S, Wzw, Wh, Wzc, Wit, ws);
        petnn_fused9<<<dim3(1024), dim3(512), 0, stream>>>(
            Xb, Sb, wb, bzw, bh, bzc, bit_, out);
    } else {
        __bf16* wb = (__bf16*)d_ws;
        petnn_cvtw<<<dim3(1536), dim3(256), 0, stream>>>(Wzw, Wh, Wzc, Wit, wb);
        petnn_fused<<<dim3(2048), dim3(512), 0, stream>>>(
            X, S, wb, bzw, bh, bzc, bit_, out);
    }
    petnn_zeroT<<<dim3(64), dim3(256), 0, stream>>>(out + 2 * (size_t)BROWS * DDIM);
}

// Round 13
// 107.885 us; speedup vs baseline: 1.0551x; 1.0374x over previous
//
#include <hip/hip_runtime.h>
#include <stdint.h>

// PETNNCell collapse (proven analytically):
//   T_t == 0, m == 1;  C_new = I_t + Z_c;  h = sigmoid(X @ W_h[:, :512]^T + b_h)
//   S_new = sigmoid((1 - Z_w)*S_prev + Z_w*h + X)
//
// R13: faithful m201 phase discipline. The one element never reproduced in
// R8-R12: frag ds_reads issued BEFORE the phase barrier (latency absorbed by
// barrier skew; lgkmcnt(0) after the barrier is ~free), with the counted
// vmcnt placed >=1 phase before the data it certifies is consumed.
// Geometry: BM=128 x BN=128 (P||Q), fam-split, 8 waves (2M x 4N), acc 64,
// 3-buffer LDS (144 KiB), prefetch distance 2 tiles, vmcnt never 0 until
// the last tiles. No sched_barrier in the loop.

#define BROWS 16384
#define DDIM  512

typedef __bf16 bf16x8 __attribute__((ext_vector_type(8)));
typedef __bf16 bf16x4 __attribute__((ext_vector_type(4)));
typedef float  f32x4  __attribute__((ext_vector_type(4)));

__device__ __forceinline__ float sigf(float x) { return 1.0f / (1.0f + __expf(-x)); }

__device__ __forceinline__ bf16x4 cvt4(f32x4 v) {
    bf16x4 r;
    r[0] = (__bf16)v[0]; r[1] = (__bf16)v[1];
    r[2] = (__bf16)v[2]; r[3] = (__bf16)v[3];
    return r;
}

__device__ __forceinline__ void glds16(const __bf16* g, __bf16* l) {
    __builtin_amdgcn_global_load_lds(
        (const __attribute__((address_space(1))) void*)g,
        (__attribute__((address_space(3))) void*)l, 16, 0, 0);
}

template<int N> __device__ __forceinline__ void waitvm() {
    if constexpr (N == 0)      asm volatile("s_waitcnt vmcnt(0)" ::: "memory");
    else if constexpr (N == 4) asm volatile("s_waitcnt vmcnt(4)" ::: "memory");
    else if constexpr (N == 6) asm volatile("s_waitcnt vmcnt(6)" ::: "memory");
    /* N < 0: no wait */
}

#define BAR   __builtin_amdgcn_s_barrier()
#define LGKM0 asm volatile("s_waitcnt lgkmcnt(0)" ::: "memory")
#define MEMF  asm volatile("" ::: "memory")

// ===================== prepass: X, S, weights -> bf16 =====================
// ws elems: [0) Xb 8388608 | [8388608) Sb 8388608 | [16777216) weights:
//   +0 Wzw 512x1024 | +524288 Wh' 512x512 | +786432 Wzc 512x1024 | +1310720 Wit 512x512
__global__ __launch_bounds__(256)
void petnn_cvt(const float* __restrict__ X,   const float* __restrict__ S,
               const float* __restrict__ Wzw, const float* __restrict__ Wh,
               const float* __restrict__ Wzc, const float* __restrict__ Wit,
               __bf16* __restrict__ ws)
{
    const int i = blockIdx.x * 256 + threadIdx.x;   // f32x4 chunk, 4587520 total
    const float* src; size_t dst;
    if (i < 2097152)      { src = X + (size_t)i * 4; dst = (size_t)i * 4; }
    else if (i < 4194304) { const int j = i - 2097152;
                            src = S + (size_t)j * 4; dst = 8388608 + (size_t)j * 4; }
    else {
        const int j = i - 4194304;                  // 0..393215 (weights)
        if (j < 131072)      { src = Wzw + (size_t)j * 4;
                               dst = 16777216 + (size_t)j * 4; }
        else if (j < 196608) { const int jj = j - 131072;   // Wh cols 0..511
                               src = Wh + (size_t)(jj >> 7) * 1024 + (jj & 127) * 4;
                               dst = 16777216 + 524288 + (size_t)jj * 4; }
        else if (j < 327680) { const int jj = j - 196608;
                               src = Wzc + (size_t)jj * 4;
                               dst = 16777216 + 786432 + (size_t)jj * 4; }
        else                 { const int jj = j - 327680;
                               src = Wit + (size_t)jj * 4;
                               dst = 16777216 + 1310720 + (size_t)jj * 4; }
    }
    *(bf16x4*)(ws + dst) = cvt4(*(const f32x4*)src);
}

// ===================== main: m201-discipline fused GEMM =====================
// BM=128 x BN=128 (P||Q), BK=64, 16 K-tiles (Q only kt<8). 512 thr = 8 waves
// 2(M) x 4(N); wave tile 64x32 per output; acc 64 regs/thread.
// LDS: sA 3x16K + sB 3x32K = 144 KiB (3-deep, prefetch distance 2).
__global__ __launch_bounds__(512, 2)
void petnn_fusedA(const __bf16* __restrict__ Xb, const __bf16* __restrict__ Sb,
                  const __bf16* __restrict__ wb,
                  const float* __restrict__ bzw, const float* __restrict__ bh,
                  const float* __restrict__ bzc, const float* __restrict__ bit_,
                  float* __restrict__ out)
{
    __shared__ __align__(16) __bf16 sA[3 * 128 * 64];        // 48 KiB
    __shared__ __align__(16) __bf16 sB[3 * 2 * 128 * 64];    // 96 KiB [buf][P/Q][c][k]

    const int tid = threadIdx.x;
    const int bid = blockIdx.x;
    // XCD-chunked swizzle (1024 wgs, bijective; HW XCD = bid & 7): per XCD
    // 16 mblk x (4 nblk x 2 fam) consecutive -> A panel shared 8x in L2.
    const int orig = (bid & 7) * 128 + (bid >> 3);
    const int fam  = orig & 1;
    const int nblk = (orig >> 1) & 3;
    const int mblk = orig >> 3;            // 0..127

    const int lane = tid & 63, wid = tid >> 6;
    const int wm = wid >> 2;               // 0..1 (64-row half of 128)
    const int wn = wid & 3;                // 0..3 (32-col slice of 128)
    const int l15 = lane & 15;
    const int kq  = (lane >> 4) * 8;

    const int arow0 = mblk * 128;
    const int ncol0 = nblk * 128;

    // staging sources (XOR swizzle baked into GLOBAL addr; LDS dest linear):
    // thread t stages row/col (t>>3) of each 64-row group, chunk (t&7).
    const int gr   = tid >> 3;             // 0..63
    const int gswz = ((tid & 7) ^ (gr & 7)) << 3;
    const __bf16* pXA = Xb + (size_t)(arow0 + gr) * 512 + gswz;
    const __bf16* pSA = Sb + (size_t)(arow0 + gr) * 512 + gswz;
    const __bf16* wbase = wb + (size_t)fam * 786432;
    const __bf16* pP = wbase + (size_t)(ncol0 + gr) * 1024 + gswz;           // K=1024
    const __bf16* pQ = wbase + 524288 + (size_t)(ncol0 + gr) * 512 + gswz;   // K=512

    // fragment read offsets (elems within one buffer slot)
    int aoff[2][4], boff[2][2];
    #pragma unroll
    for (int f = 0; f < 4; ++f) {
        const int r = wm * 64 + f * 16 + l15;
        aoff[0][f] = r * 64 + (kq        ^ ((r & 7) * 8));
        aoff[1][f] = r * 64 + ((32 + kq) ^ ((r & 7) * 8));
    }
    #pragma unroll
    for (int f = 0; f < 2; ++f) {
        const int c = wn * 32 + f * 16 + l15;
        boff[0][f] = c * 64 + (kq        ^ ((c & 7) * 8));
        boff[1][f] = c * 64 + ((32 + kq) ^ ((c & 7) * 8));
    }

    f32x4 accP[4][2] = {}, accQ[4][2] = {};

    // issue units (2 glds = 16 KiB each); buffer slot = T % 3
#define ISSUE_A(T) if ((T) < 16) { \
        const __bf16* ab_ = ((T) < 8) ? pXA : pSA; \
        const int kg_ = ((T) & 7) * 64; \
        __bf16* d_ = sA + ((T) % 3) * 8192 + tid * 8; \
        glds16(ab_ + kg_, d_); \
        glds16(ab_ + 64 * 512 + kg_, d_ + 4096); }
#define ISSUE_P(T) if ((T) < 16) { \
        __bf16* d_ = sB + ((T) % 3) * 16384 + tid * 8; \
        glds16(pP + (T) * 64, d_); \
        glds16(pP + 64 * 1024 + (T) * 64, d_ + 4096); }
#define ISSUE_Q(T) if ((T) < 8) { \
        __bf16* d_ = sB + ((T) % 3) * 16384 + 8192 + tid * 8; \
        glds16(pQ + (T) * 64, d_); \
        glds16(pQ + 64 * 512 + (T) * 64, d_ + 4096); }

    // Full tile (T<8): 2 phases. Each phase: 8 ds_reads (BEFORE barrier) ->
    // glds issue -> [ph1: counted vmcnt for tile T+1's data, consumed only
    // after the next barrier] -> BAR -> lgkm0 -> prio 16-MFMA -> BAR.
#define STEPF(T, W) { \
        const __bf16* aS_ = sA + ((T) % 3) * 8192; \
        const __bf16* bS_ = sB + ((T) % 3) * 16384; \
        { /* ph0: kk0, P+Q */ \
            bf16x8 af[4], bp[2], bq[2]; \
            _Pragma("unroll") \
            for (int f = 0; f < 4; ++f) af[f] = *(const bf16x8*)(aS_ + aoff[0][f]); \
            _Pragma("unroll") \
            for (int f = 0; f < 2; ++f) { \
                bp[f] = *(const bf16x8*)(bS_ + boff[0][f]); \
                bq[f] = *(const bf16x8*)(bS_ + 8192 + boff[0][f]); \
            } \
            MEMF; \
            ISSUE_A((T) + 2) ISSUE_P((T) + 2) \
            MEMF; BAR; LGKM0; \
            __builtin_amdgcn_s_setprio(1); \
            _Pragma("unroll") \
            for (int nf = 0; nf < 2; ++nf) \
                _Pragma("unroll") \
                for (int mf = 0; mf < 4; ++mf) { \
                    accP[mf][nf] = __builtin_amdgcn_mfma_f32_16x16x32_bf16(af[mf], bp[nf], accP[mf][nf], 0, 0, 0); \
                    accQ[mf][nf] = __builtin_amdgcn_mfma_f32_16x16x32_bf16(af[mf], bq[nf], accQ[mf][nf], 0, 0, 0); \
                } \
            __builtin_amdgcn_s_setprio(0); \
            MEMF; BAR; \
        } \
        { /* ph1: kk1, P+Q */ \
            bf16x8 af[4], bp[2], bq[2]; \
            _Pragma("unroll") \
            for (int f = 0; f < 4; ++f) af[f] = *(const bf16x8*)(aS_ + aoff[1][f]); \
            _Pragma("unroll") \
            for (int f = 0; f < 2; ++f) { \
                bp[f] = *(const bf16x8*)(bS_ + boff[1][f]); \
                bq[f] = *(const bf16x8*)(bS_ + 8192 + boff[1][f]); \
            } \
            MEMF; \
            ISSUE_Q((T) + 2) \
            waitvm<W>(); \
            MEMF; BAR; LGKM0; \
            __builtin_amdgcn_s_setprio(1); \
            _Pragma("unroll") \
            for (int nf = 0; nf < 2; ++nf) \
                _Pragma("unroll") \
                for (int mf = 0; mf < 4; ++mf) { \
                    accP[mf][nf] = __builtin_amdgcn_mfma_f32_16x16x32_bf16(af[mf], bp[nf], accP[mf][nf], 0, 0, 0); \
                    accQ[mf][nf] = __builtin_amdgcn_mfma_f32_16x16x32_bf16(af[mf], bq[nf], accQ[mf][nf], 0, 0, 0); \
                } \
            __builtin_amdgcn_s_setprio(0); \
            MEMF; BAR; \
        } }

    // Tail tile (T>=8, P only): ONE phase (12 reads, 16 MFMA).
#define STEPT(T, W) { \
        const __bf16* aS_ = sA + ((T) % 3) * 8192; \
        const __bf16* bS_ = sB + ((T) % 3) * 16384; \
        bf16x8 a0[4], a1[4], p0[2], p1[2]; \
        _Pragma("unroll") \
        for (int f = 0; f < 4; ++f) { \
            a0[f] = *(const bf16x8*)(aS_ + aoff[0][f]); \
            a1[f] = *(const bf16x8*)(aS_ + aoff[1][f]); \
        } \
        _Pragma("unroll") \
        for (int f = 0; f < 2; ++f) { \
            p0[f] = *(const bf16x8*)(bS_ + boff[0][f]); \
            p1[f] = *(const bf16x8*)(bS_ + boff[1][f]); \
        } \
        MEMF; \
        ISSUE_A((T) + 2) ISSUE_P((T) + 2) \
        waitvm<W>(); \
        MEMF; BAR; LGKM0; \
        __builtin_amdgcn_s_setprio(1); \
        _Pragma("unroll") \
        for (int nf = 0; nf < 2; ++nf) \
            _Pragma("unroll") \
            for (int mf = 0; mf < 4; ++mf) \
                accP[mf][nf] = __builtin_amdgcn_mfma_f32_16x16x32_bf16(a0[mf], p0[nf], accP[mf][nf], 0, 0, 0); \
        _Pragma("unroll") \
        for (int nf = 0; nf < 2; ++nf) \
            _Pragma("unroll") \
            for (int mf = 0; mf < 4; ++mf) \
                accP[mf][nf] = __builtin_amdgcn_mfma_f32_16x16x32_bf16(a1[mf], p1[nf], accP[mf][nf], 0, 0, 0); \
        __builtin_amdgcn_s_setprio(0); \
        MEMF; BAR; }

    // prologue: tiles 0 and 1 fully issued; retire tile 0, leave tile 1 in flight
    ISSUE_A(0) ISSUE_P(0) ISSUE_Q(0)
    ISSUE_A(1) ISSUE_P(1) ISSUE_Q(1)
    waitvm<6>(); MEMF; BAR;

    // vmcnt ladder (in-order retirement): W = loads of tile T+2 issued
    // during tile T = 6 (T+2 full), 4 (T+2 tail), 0/skip at the end.
    STEPF(0, 6)  STEPF(1, 6)  STEPF(2, 6)  STEPF(3, 6)
    STEPF(4, 6)  STEPF(5, 6)  STEPF(6, 4)  STEPF(7, 4)
    STEPT(8, 4)  STEPT(9, 4)  STEPT(10, 4) STEPT(11, 4)
    STEPT(12, 4) STEPT(13, 4) STEPT(14, 0) STEPT(15, -1)

#undef STEPF
#undef STEPT
#undef ISSUE_A
#undef ISSUE_P
#undef ISSUE_Q

    // ---- fused epilogue ----
    // C/D frag layout (m89/m91): col = lane&15, row = (lane>>4)*4 + reg
    const int rowb = arow0 + wm * 64;
    const int colb = ncol0 + wn * 32;
    if (fam == 0) {
        #pragma unroll
        for (int nf = 0; nf < 2; ++nf) {
            const int col = colb + nf * 16 + l15;
            const float vzw = bzw[col], vh = bh[col];
            #pragma unroll
            for (int mf = 0; mf < 4; ++mf) {
                #pragma unroll
                for (int j = 0; j < 4; ++j) {
                    const int row = rowb + mf * 16 + ((lane >> 4) << 2) + j;
                    const size_t off = (size_t)row * DDIM + col;
                    const float zw = sigf(accP[mf][nf][j] + vzw);
                    const float hh = sigf(accQ[mf][nf][j] + vh);
                    out[off] = sigf((1.0f - zw) * (float)Sb[off] + zw * hh
                                    + (float)Xb[off]);                 // S_new
                }
            }
        }
    } else {
        #pragma unroll
        for (int nf = 0; nf < 2; ++nf) {
            const int col = colb + nf * 16 + l15;
            const float vzc = bzc[col], vit = bit_[col];
            #pragma unroll
            for (int mf = 0; mf < 4; ++mf) {
                #pragma unroll
                for (int j = 0; j < 4; ++j) {
                    const int row = rowb + mf * 16 + ((lane >> 4) << 2) + j;
                    const size_t off = (size_t)row * DDIM + col;
                    out[(size_t)BROWS * DDIM + off] =
                        (accP[mf][nf][j] + vzc) + (accQ[mf][nf][j] + vit); // C_new
                }
            }
        }
    }
}

// ===================== fallback (ws too small): R4 path =====================
__global__ __launch_bounds__(256)
void petnn_cvtw(const float* __restrict__ Wzw, const float* __restrict__ Wh,
                const float* __restrict__ Wzc, const float* __restrict__ Wit,
                __bf16* __restrict__ wb)
{
    const int i = blockIdx.x * 256 + threadIdx.x;
    const float* src; size_t dst;
    if (i < 131072)      { src = Wzw + (size_t)i * 4;  dst = (size_t)i * 4; }
    else if (i < 196608) { const int j = i - 131072;
                           src = Wh + (size_t)(j >> 7) * 1024 + (j & 127) * 4;
                           dst = 524288 + (size_t)j * 4; }
    else if (i < 327680) { const int j = i - 196608;
                           src = Wzc + (size_t)j * 4;  dst = 786432 + (size_t)j * 4; }
    else                 { const int j = i - 327680;
                           src = Wit + (size_t)j * 4;  dst = 1310720 + (size_t)j * 4; }
    *(bf16x4*)(wb + dst) = cvt4(*(const f32x4*)src);
}

__global__ __launch_bounds__(512, 4)
void petnn_fused(const float* __restrict__ X,   const float* __restrict__ S,
                 const __bf16* __restrict__ wb,
                 const float* __restrict__ bzw, const float* __restrict__ bh,
                 const float* __restrict__ bzc, const float* __restrict__ bit_,
                 float* __restrict__ out)
{
    __shared__ __align__(16) __bf16 sA[128 * 64];
    __shared__ __align__(16) __bf16 sB[2 * 2 * 64 * 64];

    const int tid = threadIdx.x;
    const int bid = blockIdx.x;
    const int orig = (bid & 7) * 256 + (bid >> 3);
    const int fam  = orig & 1;
    const int nblk = (orig >> 1) & 7;
    const int mblk = orig >> 4;
    const int lane = tid & 63, wid = tid >> 6;
    const int wm = wid >> 2, wn = wid & 3;
    const int arow0 = mblk * 128, ncol0 = nblk * 64;
    const int srow = tid >> 4, skq = (tid & 15) << 2;
    const int bn = tid >> 3;
    const int bks = ((tid & 7) ^ (bn & 7)) << 3;
    const __bf16* wP = wb + (size_t)fam * 786432 + (size_t)(ncol0 + bn) * 1024 + bks;
    const __bf16* wQ = wb + (size_t)fam * 786432 + 524288 + (size_t)(ncol0 + bn) * 512 + bks;
    __bf16* ldsB = sB + tid * 8;

    f32x4 aP[4] = {}, aQ[4] = {};
    f32x4 ra[4];

    glds16(wP, ldsB);
    glds16(wQ, ldsB + 4096);
    #pragma unroll
    for (int p = 0; p < 4; ++p)
        ra[p] = *(const f32x4*)(X + (size_t)(arow0 + p * 32 + srow) * DDIM + skq);
    glds16(wP + 64, ldsB + 8192);
    glds16(wQ + 64, ldsB + 8192 + 4096);

    for (int kt = 0; kt < 16; ++kt) {
        const bool full = kt < 8;
        #pragma unroll
        for (int p = 0; p < 4; ++p) {
            const int r = p * 32 + srow;
            *(bf16x4*)(sA + r * 64 + (skq ^ ((r & 7) * 8))) = cvt4(ra[p]);
        }
        if (kt + 1 < 16) {
            const float* asrc = (kt + 1 < 8) ? X : S;
            const int kga = ((kt + 1) & 7) * 64 + skq;
            #pragma unroll
            for (int p = 0; p < 4; ++p)
                ra[p] = *(const f32x4*)(asrc + (size_t)(arow0 + p * 32 + srow) * DDIM + kga);
        }
        asm volatile("s_waitcnt lgkmcnt(0)" ::: "memory");
        __builtin_amdgcn_s_barrier();

        const __bf16* bb = sB + (kt & 1) * 8192;
        #pragma unroll
        for (int kk = 0; kk < 2; ++kk) {
            const int kbe = kk * 32 + (lane >> 4) * 8;
            bf16x8 af[4];
            #pragma unroll
            for (int mf = 0; mf < 4; ++mf) {
                const int r = wm * 64 + mf * 16 + (lane & 15);
                af[mf] = *(const bf16x8*)(sA + r * 64 + (kbe ^ ((r & 7) * 8)));
            }
            const int nr = wn * 16 + (lane & 15);
            const int sx = nr * 64 + (kbe ^ ((nr & 7) * 8));
            const bf16x8 bP = *(const bf16x8*)(bb + sx);
            #pragma unroll
            for (int mf = 0; mf < 4; ++mf)
                aP[mf] = __builtin_amdgcn_mfma_f32_16x16x32_bf16(af[mf], bP, aP[mf], 0, 0, 0);
            if (full) {
                const bf16x8 bQ = *(const bf16x8*)(bb + 4096 + sx);
                #pragma unroll
                for (int mf = 0; mf < 4; ++mf)
                    aQ[mf] = __builtin_amdgcn_mfma_f32_16x16x32_bf16(af[mf], bQ, aQ[mf], 0, 0, 0);
            }
        }

        if (kt + 1 < 16) {
            asm volatile("" ::: "memory");
            __builtin_amdgcn_s_barrier();
            asm volatile("" ::: "memory");
            if (kt + 2 < 16) {
                __bf16* bd = sB + (kt & 1) * 8192 + tid * 8;
                glds16(wP + (size_t)(kt + 2) * 64, bd);
                if (kt + 2 < 8) glds16(wQ + (size_t)(kt + 2) * 64, bd + 4096);
            }
        }
    }

    const int col  = ncol0 + wn * 16 + (lane & 15);
    const int rowb = arow0 + wm * 64;
    if (fam == 0) {
        const float vzw = bzw[col], vh = bh[col];
        #pragma unroll
        for (int mf = 0; mf < 4; ++mf) {
            #pragma unroll
            for (int j = 0; j < 4; ++j) {
                const int row = rowb + mf * 16 + ((lane >> 4) << 2) + j;
                const size_t off = (size_t)row * DDIM + col;
                const float zw = sigf(aP[mf][j] + vzw);
                const float hh = sigf(aQ[mf][j] + vh);
                out[off] = sigf((1.0f - zw) * S[off] + zw * hh + X[off]);
            }
        }
    } else {
        const float vzc = bzc[col], vit = bit_[col];
        #pragma unroll
        for (int mf = 0; mf < 4; ++mf) {
            #pragma unroll
            for (int j = 0; j < 4; ++j) {
                const int row = rowb + mf * 16 + ((lane >> 4) << 2) + j;
                const size_t off = (size_t)row * DDIM + col;
                out[(size_t)BROWS * DDIM + off] =
                    (aP[mf][j] + vzc) + (aQ[mf][j] + vit);
            }
        }
    }
}

__global__ void petnn_zeroT(float* __restrict__ t) {
    t[blockIdx.x * 256 + threadIdx.x] = 0.0f;   // T_t == 0 exactly
}

extern "C" void kernel_launch(void* const* d_in, const int* in_sizes, int n_in,
                              void* d_out, int out_size, void* d_ws, size_t ws_size,
                              hipStream_t stream) {
    (void)in_sizes; (void)n_in; (void)out_size;
    const float* X    = (const float*)d_in[0];
    const float* S    = (const float*)d_in[1];
    const float* Wzc  = (const float*)d_in[6];
    const float* bzc  = (const float*)d_in[7];
    const float* Wzw  = (const float*)d_in[8];
    const float* bzw  = (const float*)d_in[9];
    const float* Wit  = (const float*)d_in[10];
    const float* bit_ = (const float*)d_in[11];
    const float* Wh   = (const float*)d_in[14];
    const float* bh   = (const float*)d_in[15];
    float* out = (float*)d_out;

    if (ws_size >= 36700160u) {
        __bf16* ws = (__bf16*)d_ws;
        const __bf16* Xb = ws;
        const __bf16* Sb = ws + 8388608;
        const __bf16* wb = ws + 16777216;
        petnn_cvt<<<dim3(17920), dim3(256), 0, stream>>>(X, S, Wzw, Wh, Wzc, Wit, ws);
        petnn_fusedA<<<dim3(1024), dim3(512), 0, stream>>>(
            Xb, Sb, wb, bzw, bh, bzc, bit_, out);
    } else {
        __bf16* wb = (__bf16*)d_ws;
        petnn_cvtw<<<dim3(1536), dim3(256), 0, stream>>>(Wzw, Wh, Wzc, Wit, wb);
        petnn_fused<<<dim3(2048), dim3(512), 0, stream>>>(
            X, S, wb, bzw, bh, bzc, bit_, out);
    }
    petnn_zeroT<<<dim3(64), dim3(256), 0, stream>>>(out + 2 * (size_t)BROWS * DDIM);
}

// Round 14
// 90.186 us; speedup vs baseline: 1.2622x; 1.1962x over previous
//
#include <hip/hip_runtime.h>
#include <stdint.h>

// PETNNCell collapse (proven analytically):
//   T_t == 0, m == 1;  C_new = I_t + Z_c;  h = sigmoid(X @ W_h[:, :512]^T + b_h)
//   S_new = sigmoid((1 - Z_w)*S_prev + Z_w*h + X)
//
// R14: raise block arithmetic intensity (the one constant across the 6-round
// 85-us plateau): merge the fam-split -> one block computes ALL 4 outputs for
// BM=256 x BN=64 (112 FLOP/B from L2 vs 79 before). BK=32, 32 K-tiles,
// 8 waves, wave tile 64x32x4outs (acc 128). 4-slot LDS rotation (mod-4,
// 128 KiB) enables counted vmcnt (8/7/6/3/0 ladder, depth-2 prefetch) with a
// SINGLE barrier per tile and no drains: slot (T+2)&3 differs from the slots
// any wave can still be reading. Rolled loops (small I-footprint). Swizzle
// for 64-B rows: chunk ^= (row>>1)&3 (2-way max = conflict-free), baked into
// the glds global source address; LDS stays linear.

#define BROWS 16384
#define DDIM  512

typedef __bf16 bf16x8 __attribute__((ext_vector_type(8)));
typedef __bf16 bf16x4 __attribute__((ext_vector_type(4)));
typedef float  f32x4  __attribute__((ext_vector_type(4)));

__device__ __forceinline__ float sigf(float x) { return 1.0f / (1.0f + __expf(-x)); }

__device__ __forceinline__ bf16x4 cvt4(f32x4 v) {
    bf16x4 r;
    r[0] = (__bf16)v[0]; r[1] = (__bf16)v[1];
    r[2] = (__bf16)v[2]; r[3] = (__bf16)v[3];
    return r;
}

__device__ __forceinline__ void glds16(const __bf16* g, __bf16* l) {
    __builtin_amdgcn_global_load_lds(
        (const __attribute__((address_space(1))) void*)g,
        (__attribute__((address_space(3))) void*)l, 16, 0, 0);
}

template<int N> __device__ __forceinline__ void waitvm() {
    if constexpr (N == 0)      asm volatile("s_waitcnt vmcnt(0)" ::: "memory");
    else if constexpr (N == 3) asm volatile("s_waitcnt vmcnt(3)" ::: "memory");
    else if constexpr (N == 6) asm volatile("s_waitcnt vmcnt(6)" ::: "memory");
    else if constexpr (N == 7) asm volatile("s_waitcnt vmcnt(7)" ::: "memory");
    else if constexpr (N == 8) asm volatile("s_waitcnt vmcnt(8)" ::: "memory");
}

#define BAR   __builtin_amdgcn_s_barrier()
#define MEMF  asm volatile("" ::: "memory")

// ===================== prepass: X, S, weights -> bf16 (+ T_t zero) ==========
// ws elems: [0) Xb 8388608 | [8388608) Sb 8388608 | [16777216) weights:
//   +0 Wzc 512x1024 | +524288 Wzw 512x1024 | +1048576 Wit 512x512
//   | +1310720 Wh' 512x512 (cols 0..511). Total 18350080 elems = 36.7 MB.
__global__ __launch_bounds__(256)
void petnn_cvt(const float* __restrict__ X,   const float* __restrict__ S,
               const float* __restrict__ Wzc, const float* __restrict__ Wzw,
               const float* __restrict__ Wit, const float* __restrict__ Wh,
               __bf16* __restrict__ ws, float* __restrict__ outT)
{
    const int i = blockIdx.x * 256 + threadIdx.x;   // f32x4 chunk
    if (i >= 4587520) {                             // T_t == 0 exactly
        const int k = i - 4587520;                  // 0..4095
        *(f32x4*)(outT + (size_t)k * 4) = f32x4{0.f, 0.f, 0.f, 0.f};
        return;
    }
    const float* src; size_t dst;
    if (i < 2097152)      { src = X + (size_t)i * 4; dst = (size_t)i * 4; }
    else if (i < 4194304) { const int j = i - 2097152;
                            src = S + (size_t)j * 4; dst = 8388608 + (size_t)j * 4; }
    else {
        const int j = i - 4194304;                  // 0..393215 (weights)
        if (j < 131072)      { src = Wzc + (size_t)j * 4;
                               dst = 16777216 + (size_t)j * 4; }
        else if (j < 262144) { const int jj = j - 131072;
                               src = Wzw + (size_t)jj * 4;
                               dst = 16777216 + 524288 + (size_t)jj * 4; }
        else if (j < 327680) { const int jj = j - 262144;
                               src = Wit + (size_t)jj * 4;
                               dst = 16777216 + 1048576 + (size_t)jj * 4; }
        else                 { const int jj = j - 327680;   // Wh cols 0..511
                               src = Wh + (size_t)(jj >> 7) * 1024 + (jj & 127) * 4;
                               dst = 16777216 + 1310720 + (size_t)jj * 4; }
    }
    *(bf16x4*)(ws + dst) = cvt4(*(const f32x4*)src);
}

// ===================== main: 4-output high-intensity fused GEMM ==============
// BM=256 x BN=64, 4 outputs (Zc,Zw: K=1024 -> 32 tiles; It,h: K=512 -> 16).
// 512 thr = 8 waves 4(M) x 2(N); wave tile 64x32 x 4 outs; acc 128/thread.
// LDS: 4-slot rotation, per slot A 16K + B 16K -> 128 KiB, 1 block/CU.
__global__ __launch_bounds__(512, 2)
void petnn_fusedB(const __bf16* __restrict__ Xb, const __bf16* __restrict__ Sb,
                  const __bf16* __restrict__ wb,
                  const float* __restrict__ bzc, const float* __restrict__ bzw,
                  const float* __restrict__ bit_, const float* __restrict__ bh,
                  const float* __restrict__ X,  const float* __restrict__ S,
                  float* __restrict__ out)
{
    __shared__ __align__(16) __bf16 sA[4 * 8192];   // [slot][256r][32k] 64 KiB
    __shared__ __align__(16) __bf16 sB[4 * 8192];   // [slot][4o][64c][32k] 64 KiB

    const int tid = threadIdx.x;
    const int bid = blockIdx.x;
    // XCD-chunked swizzle (512 wgs, bijective; HW XCD = bid & 7), nblk-minor:
    // per XCD 8 mblk x 8 nblk; the 8 nblk siblings of an mblk co-resident ->
    // each streamed A tile fetched from L3 once, served 8x from that L2.
    const int orig = (bid & 7) * 64 + (bid >> 3);
    const int nblk = orig & 7;
    const int mblk = orig >> 3;            // 0..63

    const int lane = tid & 63, wid = tid >> 6;
    const int wm = wid >> 1;               // 0..3 (64-row slice of 256)
    const int wn = wid & 1;                // 0..1 (32-col slice of 64)
    const int l15 = lane & 15;
    const int kc  = lane >> 4;             // frag k-chunk 0..3

    const int arow0 = mblk * 256;
    const int ncol0 = nblk * 64;

    // ---- staging sources (swizzle in GLOBAL addr; LDS dest linear) ----
    // A: unit u covers rows u*128 + (t>>2), 16B chunk (t&3);
    //    source chunk = (t&3) ^ ((row>>1)&3) = (t&3) ^ ((t>>3)&3).
    const int ar   = tid >> 2;                       // 0..127
    const int aswz = ((tid & 3) ^ ((tid >> 3) & 3)) * 8;
    const __bf16* pXA = Xb + (size_t)(arow0 + ar) * 512 + aswz;
    // B: unit v: out = 2v + (t>>8), col = (t>>2)&63, chunk (t&3);
    //    source chunk = (t&3) ^ ((col>>1)&3).
    const int bcol = (tid >> 2) & 63;
    const int bswz = ((tid & 3) ^ ((bcol >> 1) & 3)) * 8;
    const int bo   = tid >> 8;                       // 0 or 1
    const __bf16* pB0 = wb + (size_t)bo * 524288               // Zc / Zw, K=1024
                           + (size_t)(ncol0 + bcol) * 1024 + bswz;
    const __bf16* pB1 = wb + 1048576 + (size_t)bo * 262144     // It / Wh', K=512
                           + (size_t)(ncol0 + bcol) * 512 + bswz;

    // ---- fragment read offsets (elems within one 8192-elem slot) ----
    int aoff[4], boff[2];
    #pragma unroll
    for (int mf = 0; mf < 4; ++mf) {
        const int r = wm * 64 + mf * 16 + l15;
        aoff[mf] = r * 32 + ((kc ^ ((r >> 1) & 3)) * 8);
    }
    #pragma unroll
    for (int nf = 0; nf < 2; ++nf) {
        const int c = wn * 32 + nf * 16 + l15;
        boff[nf] = c * 32 + ((kc ^ ((c >> 1) & 3)) * 8);
    }

    f32x4 acc[4][4][2] = {};    // [out][mf][nf]

#define ISSUE_FULL(T) { \
        const __bf16* a_ = pXA + (((T) >= 16) ? 8388608 : 0) + ((T) & 15) * 32; \
        __bf16* dA_ = sA + ((T) & 3) * 8192 + tid * 8; \
        glds16(a_, dA_); \
        glds16(a_ + 65536, dA_ + 4096); \
        __bf16* dB_ = sB + ((T) & 3) * 8192 + tid * 8; \
        glds16(pB0 + (T) * 32, dB_); \
        glds16(pB1 + (T) * 32, dB_ + 4096); }

#define ISSUE_TAIL(T) { \
        const __bf16* a_ = pXA + 8388608 + ((T) & 15) * 32; \
        __bf16* dA_ = sA + ((T) & 3) * 8192 + tid * 8; \
        glds16(a_, dA_); \
        glds16(a_ + 65536, dA_ + 4096); \
        glds16(pB0 + (T) * 32, sB + ((T) & 3) * 8192 + tid * 8); }

#define BODY_FULL(T) { \
        const __bf16* aS_ = sA + ((T) & 3) * 8192; \
        const __bf16* bS_ = sB + ((T) & 3) * 8192; \
        bf16x8 a_[4], b_[4][2]; \
        _Pragma("unroll") \
        for (int mf = 0; mf < 4; ++mf) a_[mf] = *(const bf16x8*)(aS_ + aoff[mf]); \
        _Pragma("unroll") \
        for (int o = 0; o < 4; ++o) \
            _Pragma("unroll") \
            for (int nf = 0; nf < 2; ++nf) \
                b_[o][nf] = *(const bf16x8*)(bS_ + o * 2048 + boff[nf]); \
        __builtin_amdgcn_s_setprio(1); \
        _Pragma("unroll") \
        for (int o = 0; o < 4; ++o) \
            _Pragma("unroll") \
            for (int nf = 0; nf < 2; ++nf) \
                _Pragma("unroll") \
                for (int mf = 0; mf < 4; ++mf) \
                    acc[o][mf][nf] = __builtin_amdgcn_mfma_f32_16x16x32_bf16(a_[mf], b_[o][nf], acc[o][mf][nf], 0, 0, 0); \
        __builtin_amdgcn_s_setprio(0); }

#define BODY_TAIL(T) { \
        const __bf16* aS_ = sA + ((T) & 3) * 8192; \
        const __bf16* bS_ = sB + ((T) & 3) * 8192; \
        bf16x8 a_[4], b_[2][2]; \
        _Pragma("unroll") \
        for (int mf = 0; mf < 4; ++mf) a_[mf] = *(const bf16x8*)(aS_ + aoff[mf]); \
        _Pragma("unroll") \
        for (int o = 0; o < 2; ++o) \
            _Pragma("unroll") \
            for (int nf = 0; nf < 2; ++nf) \
                b_[o][nf] = *(const bf16x8*)(bS_ + o * 2048 + boff[nf]); \
        __builtin_amdgcn_s_setprio(1); \
        _Pragma("unroll") \
        for (int o = 0; o < 2; ++o) \
            _Pragma("unroll") \
            for (int nf = 0; nf < 2; ++nf) \
                _Pragma("unroll") \
                for (int mf = 0; mf < 4; ++mf) \
                    acc[o][mf][nf] = __builtin_amdgcn_mfma_f32_16x16x32_bf16(a_[mf], b_[o][nf], acc[o][mf][nf], 0, 0, 0); \
        __builtin_amdgcn_s_setprio(0); }

    // prologue: tiles 0, 1 (4 units each)
    ISSUE_FULL(0)
    ISSUE_FULL(1)

    // Tiles 0..15 full (all 4 outputs), 16..31 tail (Zc,Zw only).
    // Per tile: issue T+2 -> counted wait for T (= loads of T+1 + T+2 still
    // in flight) -> single barrier -> body. Slot (T+2)&3 is free: every wave
    // issuing it has passed barrier T+1... (mod-4 rotation safety, see note).
    for (int kt = 0; kt < 14; ++kt) {
        ISSUE_FULL(kt + 2)
        waitvm<8>(); MEMF; BAR; MEMF;
        BODY_FULL(kt)
    }
    ISSUE_TAIL(16)
    waitvm<7>(); MEMF; BAR; MEMF;
    BODY_FULL(14)
    ISSUE_TAIL(17)
    waitvm<6>(); MEMF; BAR; MEMF;
    BODY_FULL(15)
    for (int kt = 16; kt < 30; ++kt) {
        ISSUE_TAIL(kt + 2)
        waitvm<6>(); MEMF; BAR; MEMF;
        BODY_TAIL(kt)
    }
    waitvm<3>(); MEMF; BAR; MEMF;
    BODY_TAIL(30)
    waitvm<0>(); MEMF; BAR; MEMF;
    BODY_TAIL(31)

#undef ISSUE_FULL
#undef ISSUE_TAIL
#undef BODY_FULL
#undef BODY_TAIL

    // ---- fused epilogue ----
    // C/D frag layout (m89/m91): col = lane&15, row = (lane>>4)*4 + reg
    const int rowb = arow0 + wm * 64;
    #pragma unroll
    for (int nf = 0; nf < 2; ++nf) {
        const int col = ncol0 + wn * 32 + nf * 16 + l15;
        const float vzc = bzc[col], vzw = bzw[col], vit = bit_[col], vh = bh[col];
        #pragma unroll
        for (int mf = 0; mf < 4; ++mf) {
            #pragma unroll
            for (int j = 0; j < 4; ++j) {
                const int row = rowb + mf * 16 + (lane >> 4) * 4 + j;
                const size_t off = (size_t)row * DDIM + col;
                const float zw = sigf(acc[1][mf][nf][j] + vzw);
                const float hh = sigf(acc[3][mf][nf][j] + vh);
                out[off] = sigf((1.0f - zw) * S[off] + zw * hh + X[off]);  // S_new
                out[(size_t)BROWS * DDIM + off] =
                    (acc[0][mf][nf][j] + vzc) + (acc[2][mf][nf][j] + vit); // C_new
            }
        }
    }
}

// ===================== fallback (ws too small): R4 path =====================
__global__ __launch_bounds__(256)
void petnn_cvtw(const float* __restrict__ Wzw, const float* __restrict__ Wh,
                const float* __restrict__ Wzc, const float* __restrict__ Wit,
                __bf16* __restrict__ wb)
{
    const int i = blockIdx.x * 256 + threadIdx.x;
    const float* src; size_t dst;
    if (i < 131072)      { src = Wzw + (size_t)i * 4;  dst = (size_t)i * 4; }
    else if (i < 196608) { const int j = i - 131072;
                           src = Wh + (size_t)(j >> 7) * 1024 + (j & 127) * 4;
                           dst = 524288 + (size_t)j * 4; }
    else if (i < 327680) { const int j = i - 196608;
                           src = Wzc + (size_t)j * 4;  dst = 786432 + (size_t)j * 4; }
    else                 { const int j = i - 327680;
                           src = Wit + (size_t)j * 4;  dst = 1310720 + (size_t)j * 4; }
    *(bf16x4*)(wb + dst) = cvt4(*(const f32x4*)src);
}

__global__ __launch_bounds__(512, 4)
void petnn_fused(const float* __restrict__ X,   const float* __restrict__ S,
                 const __bf16* __restrict__ wb,
                 const float* __restrict__ bzw, const float* __restrict__ bh,
                 const float* __restrict__ bzc, const float* __restrict__ bit_,
                 float* __restrict__ out)
{
    __shared__ __align__(16) __bf16 sA[128 * 64];
    __shared__ __align__(16) __bf16 sB[2 * 2 * 64 * 64];

    const int tid = threadIdx.x;
    const int bid = blockIdx.x;
    const int orig = (bid & 7) * 256 + (bid >> 3);
    const int fam  = orig & 1;
    const int nblk = (orig >> 1) & 7;
    const int mblk = orig >> 4;
    const int lane = tid & 63, wid = tid >> 6;
    const int wm = wid >> 2, wn = wid & 3;
    const int arow0 = mblk * 128, ncol0 = nblk * 64;
    const int srow = tid >> 4, skq = (tid & 15) << 2;
    const int bn = tid >> 3;
    const int bks = ((tid & 7) ^ (bn & 7)) << 3;
    const __bf16* wP = wb + (size_t)fam * 786432 + (size_t)(ncol0 + bn) * 1024 + bks;
    const __bf16* wQ = wb + (size_t)fam * 786432 + 524288 + (size_t)(ncol0 + bn) * 512 + bks;
    __bf16* ldsB = sB + tid * 8;

    f32x4 aP[4] = {}, aQ[4] = {};
    f32x4 ra[4];

    glds16(wP, ldsB);
    glds16(wQ, ldsB + 4096);
    #pragma unroll
    for (int p = 0; p < 4; ++p)
        ra[p] = *(const f32x4*)(X + (size_t)(arow0 + p * 32 + srow) * DDIM + skq);
    glds16(wP + 64, ldsB + 8192);
    glds16(wQ + 64, ldsB + 8192 + 4096);

    for (int kt = 0; kt < 16; ++kt) {
        const bool full = kt < 8;
        #pragma unroll
        for (int p = 0; p < 4; ++p) {
            const int r = p * 32 + srow;
            *(bf16x4*)(sA + r * 64 + (skq ^ ((r & 7) * 8))) = cvt4(ra[p]);
        }
        if (kt + 1 < 16) {
            const float* asrc = (kt + 1 < 8) ? X : S;
            const int kga = ((kt + 1) & 7) * 64 + skq;
            #pragma unroll
            for (int p = 0; p < 4; ++p)
                ra[p] = *(const f32x4*)(asrc + (size_t)(arow0 + p * 32 + srow) * DDIM + kga);
        }
        asm volatile("s_waitcnt lgkmcnt(0)" ::: "memory");
        __builtin_amdgcn_s_barrier();

        const __bf16* bb = sB + (kt & 1) * 8192;
        #pragma unroll
        for (int kk = 0; kk < 2; ++kk) {
            const int kbe = kk * 32 + (lane >> 4) * 8;
            bf16x8 af[4];
            #pragma unroll
            for (int mf = 0; mf < 4; ++mf) {
                const int r = wm * 64 + mf * 16 + (lane & 15);
                af[mf] = *(const bf16x8*)(sA + r * 64 + (kbe ^ ((r & 7) * 8)));
            }
            const int nr = wn * 16 + (lane & 15);
            const int sx = nr * 64 + (kbe ^ ((nr & 7) * 8));
            const bf16x8 bP = *(const bf16x8*)(bb + sx);
            #pragma unroll
            for (int mf = 0; mf < 4; ++mf)
                aP[mf] = __builtin_amdgcn_mfma_f32_16x16x32_bf16(af[mf], bP, aP[mf], 0, 0, 0);
            if (full) {
                const bf16x8 bQ = *(const bf16x8*)(bb + 4096 + sx);
                #pragma unroll
                for (int mf = 0; mf < 4; ++mf)
                    aQ[mf] = __builtin_amdgcn_mfma_f32_16x16x32_bf16(af[mf], bQ, aQ[mf], 0, 0, 0);
            }
        }

        if (kt + 1 < 16) {
            asm volatile("" ::: "memory");
            __builtin_amdgcn_s_barrier();
            asm volatile("" ::: "memory");
            if (kt + 2 < 16) {
                __bf16* bd = sB + (kt & 1) * 8192 + tid * 8;
                glds16(wP + (size_t)(kt + 2) * 64, bd);
                if (kt + 2 < 8) glds16(wQ + (size_t)(kt + 2) * 64, bd + 4096);
            }
        }
    }

    const int col  = ncol0 + wn * 16 + (lane & 15);
    const int rowb = arow0 + wm * 64;
    if (fam == 0) {
        const float vzw = bzw[col], vh = bh[col];
        #pragma unroll
        for (int mf = 0; mf < 4; ++mf) {
            #pragma unroll
            for (int j = 0; j < 4; ++j) {
                const int row = rowb + mf * 16 + ((lane >> 4) << 2) + j;
                const size_t off = (size_t)row * DDIM + col;
                const float zw = sigf(aP[mf][j] + vzw);
                const float hh = sigf(aQ[mf][j] + vh);
                out[off] = sigf((1.0f - zw) * S[off] + zw * hh + X[off]);
            }
        }
    } else {
        const float vzc = bzc[col], vit = bit_[col];
        #pragma unroll
        for (int mf = 0; mf < 4; ++mf) {
            #pragma unroll
            for (int j = 0; j < 4; ++j) {
                const int row = rowb + mf * 16 + ((lane >> 4) << 2) + j;
                const size_t off = (size_t)row * DDIM + col;
                out[(size_t)BROWS * DDIM + off] =
                    (aP[mf][j] + vzc) + (aQ[mf][j] + vit);
            }
        }
    }
}

__global__ void petnn_zeroT(float* __restrict__ t) {
    t[blockIdx.x * 256 + threadIdx.x] = 0.0f;
}

extern "C" void kernel_launch(void* const* d_in, const int* in_sizes, int n_in,
                              void* d_out, int out_size, void* d_ws, size_t ws_size,
                              hipStream_t stream) {
    (void)in_sizes; (void)n_in; (void)out_size;
    const float* X    = (const float*)d_in[0];
    const float* S    = (const float*)d_in[1];
    const float* Wzc  = (const float*)d_in[6];
    const float* bzc  = (const float*)d_in[7];
    const float* Wzw  = (const float*)d_in[8];
    const float* bzw  = (const float*)d_in[9];
    const float* Wit  = (const float*)d_in[10];
    const float* bit_ = (const float*)d_in[11];
    const float* Wh   = (const float*)d_in[14];
    const float* bh   = (const float*)d_in[15];
    float* out = (float*)d_out;

    if (ws_size >= 36700160u) {
        __bf16* ws = (__bf16*)d_ws;
        const __bf16* Xb = ws;
        const __bf16* Sb = ws + 8388608;
        const __bf16* wb = ws + 16777216;
        // prepass: 4587520 data chunks + 4096 T-zero chunks = 4591616 -> 17936 blocks
        petnn_cvt<<<dim3(17936), dim3(256), 0, stream>>>(
            X, S, Wzc, Wzw, Wit, Wh, ws, out + 2 * (size_t)BROWS * DDIM);
        petnn_fusedB<<<dim3(512), dim3(512), 0, stream>>>(
            Xb, Sb, wb, bzc, bzw, bit_, bh, X, S, out);
    } else {
        __bf16* wb = (__bf16*)d_ws;
        petnn_cvtw<<<dim3(1536), dim3(256), 0, stream>>>(Wzw, Wh, Wzc, Wit, wb);
        petnn_fused<<<dim3(2048), dim3(512), 0, stream>>>(
            X, S, wb, bzw, bh, bzc, bit_, out);
        petnn_zeroT<<<dim3(64), dim3(256), 0, stream>>>(out + 2 * (size_t)BROWS * DDIM);
    }
}

// Round 15
// 86.089 us; speedup vs baseline: 1.3223x; 1.0476x over previous
//
#include <hip/hip_runtime.h>
#include <stdint.h>

// PETNNCell collapse (proven analytically):
//   T_t == 0, m == 1;  C_new = I_t + Z_c;  h = sigmoid(X @ W_h[:, :512]^T + b_h)
//   S_new = sigmoid((1 - Z_w)*S_prev + Z_w*h + X)
//
// R15: amortize the per-tile fixed cost (~1600 cyc of sync+latency, paid
// per tile) that R14's cycle accounting exposed: BK 32->64 halves the tile
// count (16 instead of 32) while doubling per-tile MFMA work. Keep R14's
// 4-output merge (intensity 112 FLOP/B - the only lever that moved the
// plateau). 2-slot LDS rotation (128 KiB), single barrier per tile,
// depth-1 prefetch: the vmcnt(0) waits loads issued a full ~2500-cyc body
// earlier -> free. Epilogue reads bf16 Xb/Sb (halves epilogue traffic).

#define BROWS 16384
#define DDIM  512

typedef __bf16 bf16x8 __attribute__((ext_vector_type(8)));
typedef __bf16 bf16x4 __attribute__((ext_vector_type(4)));
typedef float  f32x4  __attribute__((ext_vector_type(4)));

__device__ __forceinline__ float sigf(float x) { return 1.0f / (1.0f + __expf(-x)); }

__device__ __forceinline__ bf16x4 cvt4(f32x4 v) {
    bf16x4 r;
    r[0] = (__bf16)v[0]; r[1] = (__bf16)v[1];
    r[2] = (__bf16)v[2]; r[3] = (__bf16)v[3];
    return r;
}

__device__ __forceinline__ void glds16(const __bf16* g, __bf16* l) {
    __builtin_amdgcn_global_load_lds(
        (const __attribute__((address_space(1))) void*)g,
        (__attribute__((address_space(3))) void*)l, 16, 0, 0);
}

#define BAR   __builtin_amdgcn_s_barrier()
#define VM0   asm volatile("s_waitcnt vmcnt(0)" ::: "memory")
#define MEMF  asm volatile("" ::: "memory")

// ===================== prepass: X, S, weights -> bf16 (+ T_t zero) ==========
// ws elems: [0) Xb 8388608 | [8388608) Sb 8388608 | [16777216) weights:
//   +0 Wzc 512x1024 | +524288 Wzw 512x1024 | +1048576 Wit 512x512
//   | +1310720 Wh' 512x512 (cols 0..511). Total 18350080 elems = 36.7 MB.
__global__ __launch_bounds__(256)
void petnn_cvt(const float* __restrict__ X,   const float* __restrict__ S,
               const float* __restrict__ Wzc, const float* __restrict__ Wzw,
               const float* __restrict__ Wit, const float* __restrict__ Wh,
               __bf16* __restrict__ ws, float* __restrict__ outT)
{
    const int i = blockIdx.x * 256 + threadIdx.x;   // f32x4 chunk
    if (i >= 4587520) {                             // T_t == 0 exactly
        const int k = i - 4587520;                  // 0..4095
        *(f32x4*)(outT + (size_t)k * 4) = f32x4{0.f, 0.f, 0.f, 0.f};
        return;
    }
    const float* src; size_t dst;
    if (i < 2097152)      { src = X + (size_t)i * 4; dst = (size_t)i * 4; }
    else if (i < 4194304) { const int j = i - 2097152;
                            src = S + (size_t)j * 4; dst = 8388608 + (size_t)j * 4; }
    else {
        const int j = i - 4194304;                  // 0..393215 (weights)
        if (j < 131072)      { src = Wzc + (size_t)j * 4;
                               dst = 16777216 + (size_t)j * 4; }
        else if (j < 262144) { const int jj = j - 131072;
                               src = Wzw + (size_t)jj * 4;
                               dst = 16777216 + 524288 + (size_t)jj * 4; }
        else if (j < 327680) { const int jj = j - 262144;
                               src = Wit + (size_t)jj * 4;
                               dst = 16777216 + 1048576 + (size_t)jj * 4; }
        else                 { const int jj = j - 327680;   // Wh cols 0..511
                               src = Wh + (size_t)(jj >> 7) * 1024 + (jj & 127) * 4;
                               dst = 16777216 + 1310720 + (size_t)jj * 4; }
    }
    *(bf16x4*)(ws + dst) = cvt4(*(const f32x4*)src);
}

// ===================== main: BK=64 4-output fused GEMM ======================
// BM=256 x BN=64, 4 outputs. Zc,Zw: K=1024 -> tiles 0..15 (0..7 X, 8..15 S);
// It,h: K=512 -> tiles 0..7 only. 512 thr = 8 waves 4(M) x 2(N); wave tile
// 64x32 x 4outs; acc 128/thread. LDS: 2 slots x (A 32K + B 32K) = 128 KiB.
__global__ __launch_bounds__(512, 2)
void petnn_fusedC(const __bf16* __restrict__ Xb, const __bf16* __restrict__ Sb,
                  const __bf16* __restrict__ wb,
                  const float* __restrict__ bzc, const float* __restrict__ bzw,
                  const float* __restrict__ bit_, const float* __restrict__ bh,
                  float* __restrict__ out)
{
    __shared__ __align__(16) __bf16 sA[2 * 16384];  // [slot][256r][64k] 64 KiB
    __shared__ __align__(16) __bf16 sB[2 * 16384];  // [slot][4o][64c][64k] 64 KiB

    const int tid = threadIdx.x;
    const int bid = blockIdx.x;
    // XCD-chunked swizzle (512 wgs, bijective; HW XCD = bid & 7), nblk-minor:
    // per XCD 8 mblk x 8 nblk -> each A tile fetched once per XCD's L2.
    const int orig = (bid & 7) * 64 + (bid >> 3);
    const int nblk = orig & 7;
    const int mblk = orig >> 3;            // 0..63

    const int lane = tid & 63, wid = tid >> 6;
    const int wm = wid >> 1;               // 0..3 (64-row slice of 256)
    const int wn = wid & 1;                // 0..1 (32-col slice of 64)
    const int l15 = lane & 15;
    const int kc  = lane >> 4;             // frag k-chunk 0..3

    const int arow0 = mblk * 256;
    const int ncol0 = nblk * 64;

    // ---- staging sources (XOR swizzle in GLOBAL addr; LDS dest linear) ----
    // A: unit g covers rows g*64 + (t>>3), chunk (t&7); row&7 = (t>>3)&7.
    const int gr   = tid >> 3;                       // 0..63
    const int aswz = ((tid & 7) ^ (gr & 7)) * 8;
    const __bf16* pXA = Xb + (size_t)(arow0 + gr) * 512 + aswz;
    const __bf16* pSA = Sb + (size_t)(arow0 + gr) * 512 + aswz;
    // B: unit v = output v; col = t>>3, chunk (t&7); col&7 same.
    const __bf16* pZc = wb +       0 + (size_t)(ncol0 + gr) * 1024 + aswz;  // K=1024
    const __bf16* pZw = wb +  524288 + (size_t)(ncol0 + gr) * 1024 + aswz;  // K=1024
    const __bf16* pIt = wb + 1048576 + (size_t)(ncol0 + gr) * 512  + aswz;  // K=512
    const __bf16* pH  = wb + 1310720 + (size_t)(ncol0 + gr) * 512  + aswz;  // K=512

    // ---- fragment read offsets (elems within one 16384-elem slot) ----
    int aoff[2][4], boff[2][2];
    #pragma unroll
    for (int mf = 0; mf < 4; ++mf) {
        const int r = wm * 64 + mf * 16 + l15;
        aoff[0][mf] = r * 64 + (((kc)     ^ (r & 7)) * 8);
        aoff[1][mf] = r * 64 + (((4 + kc) ^ (r & 7)) * 8);
    }
    #pragma unroll
    for (int nf = 0; nf < 2; ++nf) {
        const int c = wn * 32 + nf * 16 + l15;
        boff[0][nf] = c * 64 + (((kc)     ^ (c & 7)) * 8);
        boff[1][nf] = c * 64 + (((4 + kc) ^ (c & 7)) * 8);
    }

    f32x4 acc[4][4][2] = {};    // [out][mf][nf]

    // tile T: full (T<8): A(4 units) + B(4 units); tail (8..15): A + Zc,Zw
#define ISSUE_FULL(T) { \
        const __bf16* a_ = (((T) < 8) ? pXA : pSA) + ((T) & 7) * 64; \
        __bf16* dA_ = sA + ((T) & 1) * 16384 + tid * 8; \
        glds16(a_,         dA_); \
        glds16(a_ + 32768, dA_ + 4096); \
        glds16(a_ + 65536, dA_ + 8192); \
        glds16(a_ + 98304, dA_ + 12288); \
        __bf16* dB_ = sB + ((T) & 1) * 16384 + tid * 8; \
        glds16(pZc + (T) * 64, dB_); \
        glds16(pZw + (T) * 64, dB_ + 4096); \
        glds16(pIt + (T) * 64, dB_ + 8192); \
        glds16(pH  + (T) * 64, dB_ + 12288); }

#define ISSUE_TAIL(T) { \
        const __bf16* a_ = pSA + ((T) & 7) * 64; \
        __bf16* dA_ = sA + ((T) & 1) * 16384 + tid * 8; \
        glds16(a_,         dA_); \
        glds16(a_ + 32768, dA_ + 4096); \
        glds16(a_ + 65536, dA_ + 8192); \
        glds16(a_ + 98304, dA_ + 12288); \
        __bf16* dB_ = sB + ((T) & 1) * 16384 + tid * 8; \
        glds16(pZc + (T) * 64, dB_); \
        glds16(pZw + (T) * 64, dB_ + 4096); }

    // body: A frags once, then per-out {4 B-frag reads, 16 MFMA} - bounded
    // liveness, compiler pipelines out o+1's reads under out o's MFMAs.
#define BODY(T, NOUT) { \
        const __bf16* aS_ = sA + ((T) & 1) * 16384; \
        const __bf16* bS_ = sB + ((T) & 1) * 16384; \
        bf16x8 a_[2][4]; \
        _Pragma("unroll") \
        for (int kk = 0; kk < 2; ++kk) \
            _Pragma("unroll") \
            for (int mf = 0; mf < 4; ++mf) \
                a_[kk][mf] = *(const bf16x8*)(aS_ + aoff[kk][mf]); \
        __builtin_amdgcn_s_setprio(1); \
        _Pragma("unroll") \
        for (int o = 0; o < (NOUT); ++o) { \
            bf16x8 b_[2][2]; \
            _Pragma("unroll") \
            for (int kk = 0; kk < 2; ++kk) \
                _Pragma("unroll") \
                for (int nf = 0; nf < 2; ++nf) \
                    b_[kk][nf] = *(const bf16x8*)(bS_ + o * 4096 + boff[kk][nf]); \
            _Pragma("unroll") \
            for (int kk = 0; kk < 2; ++kk) \
                _Pragma("unroll") \
                for (int nf = 0; nf < 2; ++nf) \
                    _Pragma("unroll") \
                    for (int mf = 0; mf < 4; ++mf) \
                        acc[o][mf][nf] = __builtin_amdgcn_mfma_f32_16x16x32_bf16( \
                            a_[kk][mf], b_[kk][nf], acc[o][mf][nf], 0, 0, 0); \
        } \
        __builtin_amdgcn_s_setprio(0); }

    // ---- pipeline: single barrier per tile, depth-1 prefetch ----
    ISSUE_FULL(0)
    for (int kt = 0; kt < 8; ++kt) {
        VM0; MEMF; BAR; MEMF;
        if (kt < 7)       { ISSUE_FULL(kt + 1) }
        else              { ISSUE_TAIL(8) }
        MEMF;
        BODY(kt, 4)
    }
    for (int kt = 8; kt < 16; ++kt) {
        VM0; MEMF; BAR; MEMF;
        if (kt < 15)      { ISSUE_TAIL(kt + 1) }
        MEMF;
        BODY(kt, 2)
    }

#undef ISSUE_FULL
#undef ISSUE_TAIL
#undef BODY

    // ---- fused epilogue (bf16 Xb/Sb reads) ----
    // C/D frag layout (m89/m91): col = lane&15, row = (lane>>4)*4 + reg
    const int rowb = arow0 + wm * 64;
    #pragma unroll
    for (int nf = 0; nf < 2; ++nf) {
        const int col = ncol0 + wn * 32 + nf * 16 + l15;
        const float vzc = bzc[col], vzw = bzw[col], vit = bit_[col], vh = bh[col];
        #pragma unroll
        for (int mf = 0; mf < 4; ++mf) {
            #pragma unroll
            for (int j = 0; j < 4; ++j) {
                const int row = rowb + mf * 16 + (lane >> 4) * 4 + j;
                const size_t off = (size_t)row * DDIM + col;
                const float zw = sigf(acc[1][mf][nf][j] + vzw);
                const float hh = sigf(acc[3][mf][nf][j] + vh);
                out[off] = sigf((1.0f - zw) * (float)Sb[off] + zw * hh
                                + (float)Xb[off]);                         // S_new
                out[(size_t)BROWS * DDIM + off] =
                    (acc[0][mf][nf][j] + vzc) + (acc[2][mf][nf][j] + vit); // C_new
            }
        }
    }
}

// ===================== fallback (ws too small): R4 path =====================
__global__ __launch_bounds__(256)
void petnn_cvtw(const float* __restrict__ Wzw, const float* __restrict__ Wh,
                const float* __restrict__ Wzc, const float* __restrict__ Wit,
                __bf16* __restrict__ wb)
{
    const int i = blockIdx.x * 256 + threadIdx.x;
    const float* src; size_t dst;
    if (i < 131072)      { src = Wzw + (size_t)i * 4;  dst = (size_t)i * 4; }
    else if (i < 196608) { const int j = i - 131072;
                           src = Wh + (size_t)(j >> 7) * 1024 + (j & 127) * 4;
                           dst = 524288 + (size_t)j * 4; }
    else if (i < 327680) { const int j = i - 196608;
                           src = Wzc + (size_t)j * 4;  dst = 786432 + (size_t)j * 4; }
    else                 { const int j = i - 327680;
                           src = Wit + (size_t)j * 4;  dst = 1310720 + (size_t)j * 4; }
    *(bf16x4*)(wb + dst) = cvt4(*(const f32x4*)src);
}

__global__ __launch_bounds__(512, 4)
void petnn_fused(const float* __restrict__ X,   const float* __restrict__ S,
                 const __bf16* __restrict__ wb,
                 const float* __restrict__ bzw, const float* __restrict__ bh,
                 const float* __restrict__ bzc, const float* __restrict__ bit_,
                 float* __restrict__ out)
{
    __shared__ __align__(16) __bf16 sA[128 * 64];
    __shared__ __align__(16) __bf16 sB[2 * 2 * 64 * 64];

    const int tid = threadIdx.x;
    const int bid = blockIdx.x;
    const int orig = (bid & 7) * 256 + (bid >> 3);
    const int fam  = orig & 1;
    const int nblk = (orig >> 1) & 7;
    const int mblk = orig >> 4;
    const int lane = tid & 63, wid = tid >> 6;
    const int wm = wid >> 2, wn = wid & 3;
    const int arow0 = mblk * 128, ncol0 = nblk * 64;
    const int srow = tid >> 4, skq = (tid & 15) << 2;
    const int bn = tid >> 3;
    const int bks = ((tid & 7) ^ (bn & 7)) << 3;
    const __bf16* wP = wb + (size_t)fam * 786432 + (size_t)(ncol0 + bn) * 1024 + bks;
    const __bf16* wQ = wb + (size_t)fam * 786432 + 524288 + (size_t)(ncol0 + bn) * 512 + bks;
    __bf16* ldsB = sB + tid * 8;

    f32x4 aP[4] = {}, aQ[4] = {};
    f32x4 ra[4];

    glds16(wP, ldsB);
    glds16(wQ, ldsB + 4096);
    #pragma unroll
    for (int p = 0; p < 4; ++p)
        ra[p] = *(const f32x4*)(X + (size_t)(arow0 + p * 32 + srow) * DDIM + skq);
    glds16(wP + 64, ldsB + 8192);
    glds16(wQ + 64, ldsB + 8192 + 4096);

    for (int kt = 0; kt < 16; ++kt) {
        const bool full = kt < 8;
        #pragma unroll
        for (int p = 0; p < 4; ++p) {
            const int r = p * 32 + srow;
            *(bf16x4*)(sA + r * 64 + (skq ^ ((r & 7) * 8))) = cvt4(ra[p]);
        }
        if (kt + 1 < 16) {
            const float* asrc = (kt + 1 < 8) ? X : S;
            const int kga = ((kt + 1) & 7) * 64 + skq;
            #pragma unroll
            for (int p = 0; p < 4; ++p)
                ra[p] = *(const f32x4*)(asrc + (size_t)(arow0 + p * 32 + srow) * DDIM + kga);
        }
        asm volatile("s_waitcnt lgkmcnt(0)" ::: "memory");
        __builtin_amdgcn_s_barrier();

        const __bf16* bb = sB + (kt & 1) * 8192;
        #pragma unroll
        for (int kk = 0; kk < 2; ++kk) {
            const int kbe = kk * 32 + (lane >> 4) * 8;
            bf16x8 af[4];
            #pragma unroll
            for (int mf = 0; mf < 4; ++mf) {
                const int r = wm * 64 + mf * 16 + (lane & 15);
                af[mf] = *(const bf16x8*)(sA + r * 64 + (kbe ^ ((r & 7) * 8)));
            }
            const int nr = wn * 16 + (lane & 15);
            const int sx = nr * 64 + (kbe ^ ((nr & 7) * 8));
            const bf16x8 bP = *(const bf16x8*)(bb + sx);
            #pragma unroll
            for (int mf = 0; mf < 4; ++mf)
                aP[mf] = __builtin_amdgcn_mfma_f32_16x16x32_bf16(af[mf], bP, aP[mf], 0, 0, 0);
            if (full) {
                const bf16x8 bQ = *(const bf16x8*)(bb + 4096 + sx);
                #pragma unroll
                for (int mf = 0; mf < 4; ++mf)
                    aQ[mf] = __builtin_amdgcn_mfma_f32_16x16x32_bf16(af[mf], bQ, aQ[mf], 0, 0, 0);
            }
        }

        if (kt + 1 < 16) {
            asm volatile("" ::: "memory");
            __builtin_amdgcn_s_barrier();
            asm volatile("" ::: "memory");
            if (kt + 2 < 16) {
                __bf16* bd = sB + (kt & 1) * 8192 + tid * 8;
                glds16(wP + (size_t)(kt + 2) * 64, bd);
                if (kt + 2 < 8) glds16(wQ + (size_t)(kt + 2) * 64, bd + 4096);
            }
        }
    }

    const int col  = ncol0 + wn * 16 + (lane & 15);
    const int rowb = arow0 + wm * 64;
    if (fam == 0) {
        const float vzw = bzw[col], vh = bh[col];
        #pragma unroll
        for (int mf = 0; mf < 4; ++mf) {
            #pragma unroll
            for (int j = 0; j < 4; ++j) {
                const int row = rowb + mf * 16 + ((lane >> 4) << 2) + j;
                const size_t off = (size_t)row * DDIM + col;
                const float zw = sigf(aP[mf][j] + vzw);
                const float hh = sigf(aQ[mf][j] + vh);
                out[off] = sigf((1.0f - zw) * S[off] + zw * hh + X[off]);
            }
        }
    } else {
        const float vzc = bzc[col], vit = bit_[col];
        #pragma unroll
        for (int mf = 0; mf < 4; ++mf) {
            #pragma unroll
            for (int j = 0; j < 4; ++j) {
                const int row = rowb + mf * 16 + ((lane >> 4) << 2) + j;
                const size_t off = (size_t)row * DDIM + col;
                out[(size_t)BROWS * DDIM + off] =
                    (aP[mf][j] + vzc) + (aQ[mf][j] + vit);
            }
        }
    }
}

__global__ void petnn_zeroT(float* __restrict__ t) {
    t[blockIdx.x * 256 + threadIdx.x] = 0.0f;
}

extern "C" void kernel_launch(void* const* d_in, const int* in_sizes, int n_in,
                              void* d_out, int out_size, void* d_ws, size_t ws_size,
                              hipStream_t stream) {
    (void)in_sizes; (void)n_in; (void)out_size;
    const float* X    = (const float*)d_in[0];
    const float* S    = (const float*)d_in[1];
    const float* Wzc  = (const float*)d_in[6];
    const float* bzc  = (const float*)d_in[7];
    const float* Wzw  = (const float*)d_in[8];
    const float* bzw  = (const float*)d_in[9];
    const float* Wit  = (const float*)d_in[10];
    const float* bit_ = (const float*)d_in[11];
    const float* Wh   = (const float*)d_in[14];
    const float* bh   = (const float*)d_in[15];
    float* out = (float*)d_out;

    if (ws_size >= 36700160u) {
        __bf16* ws = (__bf16*)d_ws;
        const __bf16* Xb = ws;
        const __bf16* Sb = ws + 8388608;
        const __bf16* wb = ws + 16777216;
        petnn_cvt<<<dim3(17936), dim3(256), 0, stream>>>(
            X, S, Wzc, Wzw, Wit, Wh, ws, out + 2 * (size_t)BROWS * DDIM);
        petnn_fusedC<<<dim3(512), dim3(512), 0, stream>>>(
            Xb, Sb, wb, bzc, bzw, bit_, bh, out);
    } else {
        __bf16* wb = (__bf16*)d_ws;
        petnn_cvtw<<<dim3(1536), dim3(256), 0, stream>>>(Wzw, Wh, Wzc, Wit, wb);
        petnn_fused<<<dim3(2048), dim3(512), 0, stream>>>(
            X, S, wb, bzw, bh, bzc, bit_, out);
        petnn_zeroT<<<dim3(64), dim3(256), 0, stream>>>(out + 2 * (size_t)BROWS * DDIM);
    }
}